// Round 2
// baseline (978.379 us; speedup 1.0000x reference)
//
#include <hip/hip_runtime.h>
#include <math.h>

#define N_NODES 50000
#define E_EDGES 500000
#define F_IN    128
#define HDIM    128
#define OUTC    2
#define NGRAPH  512

// ---------------- utility: zero a span of 4-byte words ----------------
__global__ void k_zero(int* __restrict__ p, int n) {
    int i = blockIdx.x * blockDim.x + threadIdx.x;
    int stride = gridDim.x * blockDim.x;
    for (; i < n; i += stride) p[i] = 0;
}

// ---------------- edge histogram over dst ----------------
__global__ void k_hist(const int* __restrict__ dst, int* __restrict__ cnt) {
    int i = blockIdx.x * blockDim.x + threadIdx.x;
    int stride = gridDim.x * blockDim.x;
    for (; i < E_EDGES; i += stride) atomicAdd(&cnt[dst[i]], 1);
}

// ---------------- scan stage A: per-block exclusive scan of edge counts ----
__global__ void k_scan_a(const int* __restrict__ cnt, int* __restrict__ excl,
                         int* __restrict__ blksum, float* __restrict__ dinv,
                         const int* __restrict__ batch, float* __restrict__ cnt_g) {
    __shared__ int s[512];
    int t = threadIdx.x;
    int i = blockIdx.x * 512 + t;
    int v = 0;
    if (i < N_NODES) {
        v = cnt[i];
        dinv[i] = 1.0f / sqrtf((float)(v + 1));
        atomicAdd(&cnt_g[batch[i]], 1.0f);
    }
    s[t] = v; __syncthreads();
    for (int off = 1; off < 512; off <<= 1) {
        int add = (t >= off) ? s[t - off] : 0;
        __syncthreads();
        s[t] += add;
        __syncthreads();
    }
    if (i < N_NODES) excl[i] = s[t] - v;     // exclusive within block
    if (t == 511) blksum[blockIdx.x] = s[511];
}

// ---------------- scan stage B: exclusive scan of block sums (single block) --
__global__ void k_scan_b(int* __restrict__ blksum, int nb) {
    __shared__ int s[512];
    int t = threadIdx.x;
    int v = (t < nb) ? blksum[t] : 0;
    s[t] = v; __syncthreads();
    for (int off = 1; off < 512; off <<= 1) {
        int add = (t >= off) ? s[t - off] : 0;
        __syncthreads();
        s[t] += add;
        __syncthreads();
    }
    if (t < nb) blksum[t] = s[t] - v;        // exclusive, in place
}

// ---------------- scan stage C: add block offsets, finalize row_ptr --------
__global__ void k_scan_c(int* __restrict__ excl, const int* __restrict__ blksum) {
    int t = threadIdx.x;
    int i = blockIdx.x * 512 + t;
    if (i < N_NODES) excl[i] += blksum[blockIdx.x];
    if (i == 0) excl[N_NODES] = E_EDGES;
}

// ---------------- CSR fill: scatter (src, weight) records grouped by dst ---
// edge weight dinv[s]*dinv[d] is precomputed here so k_agg's inner loop has
// no shuffles and no weight gathers.
__global__ void k_fill(const int* __restrict__ src, const int* __restrict__ dst,
                       const int* __restrict__ row_ptr, int* __restrict__ fill_cnt,
                       const float* __restrict__ dinv, int2* __restrict__ edges) {
    int i = blockIdx.x * blockDim.x + threadIdx.x;
    int stride = gridDim.x * blockDim.x;
    for (; i < E_EDGES; i += stride) {
        int d = dst[i];
        int s = src[i];
        int p = atomicAdd(&fill_cnt[d], 1);
        float w = dinv[s] * dinv[d];
        edges[row_ptr[d] + p] = make_int2(s, __float_as_int(w));
    }
}

// ---------------- generic fp32 GEMM: C = act(A@B + bias) -------------------
// used for the small pool/head GEMMs only.
__global__ __launch_bounds__(256) void k_gemm(
        const float* __restrict__ A, const float* __restrict__ B,
        const float* __restrict__ bias, float* __restrict__ C,
        int M, int Nn, int K, int ldc, int act) {
    __shared__ float As[16][64];
    __shared__ float Bs[16][68];
    int tid = threadIdx.x;
    int tx = tid & 15, ty = tid >> 4;
    int row0 = blockIdx.x * 64, col0 = blockIdx.y * 64;
    float acc[4][4] = {};
    int arow = tid >> 2;
    int acol = (tid & 3) * 4;
    int brow = tid >> 4;
    int bcol = (tid & 15) * 4;

    for (int k0 = 0; k0 < K; k0 += 16) {
        float4 av = make_float4(0.f, 0.f, 0.f, 0.f);
        int ar = row0 + arow;
        if (ar < M) av = *(const float4*)(A + (size_t)ar * K + k0 + acol);
        As[acol + 0][arow] = av.x;
        As[acol + 1][arow] = av.y;
        As[acol + 2][arow] = av.z;
        As[acol + 3][arow] = av.w;

        float4 bv = make_float4(0.f, 0.f, 0.f, 0.f);
        const float* Brow = B + (size_t)(k0 + brow) * Nn;
        int bc = col0 + bcol;
        if (bc + 3 < Nn) {
            bv = *(const float4*)(Brow + bc);
        } else {
            if (bc     < Nn) bv.x = Brow[bc];
            if (bc + 1 < Nn) bv.y = Brow[bc + 1];
            if (bc + 2 < Nn) bv.z = Brow[bc + 2];
        }
        Bs[brow][bcol + 0] = bv.x;
        Bs[brow][bcol + 1] = bv.y;
        Bs[brow][bcol + 2] = bv.z;
        Bs[brow][bcol + 3] = bv.w;
        __syncthreads();

#pragma unroll
        for (int k = 0; k < 16; k++) {
            float4 a = *(const float4*)&As[k][ty * 4];
            float4 b = *(const float4*)&Bs[k][tx * 4];
            acc[0][0] += a.x * b.x; acc[0][1] += a.x * b.y; acc[0][2] += a.x * b.z; acc[0][3] += a.x * b.w;
            acc[1][0] += a.y * b.x; acc[1][1] += a.y * b.y; acc[1][2] += a.y * b.z; acc[1][3] += a.y * b.w;
            acc[2][0] += a.z * b.x; acc[2][1] += a.z * b.y; acc[2][2] += a.z * b.z; acc[2][3] += a.z * b.w;
            acc[3][0] += a.w * b.x; acc[3][1] += a.w * b.y; acc[3][2] += a.w * b.z; acc[3][3] += a.w * b.w;
        }
        __syncthreads();
    }

#pragma unroll
    for (int i = 0; i < 4; i++) {
        int r = row0 + ty * 4 + i;
        if (r >= M) continue;
#pragma unroll
        for (int j = 0; j < 4; j++) {
            int c = col0 + tx * 4 + j;
            if (c >= Nn) continue;
            float v = acc[i][j];
            if (bias) v += bias[c];
            if (act) v = fmaxf(v, 0.0f);
            C[(size_t)r * ldc + c] = v;
        }
    }
}

// ---------------- specialized fp32 GEMM for N=K=128 (node-feature layers) --
// 128x128 block tile, 8x8 micro-tile, BK=16. C = A@B (no bias/act; those are
// fused into k_agg). LDS bytes/FMA = 1.0 (vs 2.0 in k_gemm) -> VALU-bound.
__global__ __launch_bounds__(256) void k_gemm128(
        const float* __restrict__ A, const float* __restrict__ Bg,
        float* __restrict__ C, int M) {
    __shared__ float As[16][128];
    __shared__ float Bs[16 * 128];
    int tid = threadIdx.x;
    int tx = tid & 15, ty = tid >> 4;
    int row0 = blockIdx.x * 128;
    float acc[8][8] = {};

    int arow = tid >> 1;                // 0..127
    int akc  = (tid & 1) * 8;           // 0 or 8
    const float* Aptr = A + (size_t)(row0 + arow) * 128 + akc;
    bool aok = (row0 + arow) < M;
    const float4* Bv = (const float4*)Bg;
    float4* Bsv = (float4*)Bs;

    for (int k0 = 0; k0 < 128; k0 += 16) {
        float4 a0 = make_float4(0.f, 0.f, 0.f, 0.f), a1 = a0;
        if (aok) {
            a0 = *(const float4*)(Aptr + k0);
            a1 = *(const float4*)(Aptr + k0 + 4);
        }
        float4 b0 = Bv[k0 * 32 + tid];
        float4 b1 = Bv[k0 * 32 + tid + 256];
        __syncthreads();                // previous-iter LDS readers done
        As[akc + 0][arow] = a0.x; As[akc + 1][arow] = a0.y;
        As[akc + 2][arow] = a0.z; As[akc + 3][arow] = a0.w;
        As[akc + 4][arow] = a1.x; As[akc + 5][arow] = a1.y;
        As[akc + 6][arow] = a1.z; As[akc + 7][arow] = a1.w;
        Bsv[tid] = b0;
        Bsv[tid + 256] = b1;
        __syncthreads();
#pragma unroll
        for (int k = 0; k < 16; k++) {
            float4 am0 = *(const float4*)&As[k][ty * 8];
            float4 am1 = *(const float4*)&As[k][ty * 8 + 4];
            float4 bn0 = *(const float4*)&Bs[k * 128 + tx * 4];        // cols tx*4..+3
            float4 bn1 = *(const float4*)&Bs[k * 128 + 64 + tx * 4];   // cols 64+tx*4..+3
            float am[8] = {am0.x, am0.y, am0.z, am0.w, am1.x, am1.y, am1.z, am1.w};
            float bn[8] = {bn0.x, bn0.y, bn0.z, bn0.w, bn1.x, bn1.y, bn1.z, bn1.w};
#pragma unroll
            for (int i = 0; i < 8; i++)
#pragma unroll
                for (int j = 0; j < 8; j++)
                    acc[i][j] += am[i] * bn[j];
        }
    }

#pragma unroll
    for (int i = 0; i < 8; i++) {
        int r = row0 + ty * 8 + i;
        if (r >= M) continue;
        *(float4*)(C + (size_t)r * 128 + tx * 4) =
            make_float4(acc[i][0], acc[i][1], acc[i][2], acc[i][3]);
        *(float4*)(C + (size_t)r * 128 + 64 + tx * 4) =
            make_float4(acc[i][4], acc[i][5], acc[i][6], acc[i][7]);
    }
}

// ---------------- CSR aggregation (wave per node, 2x32-lane halves) --------
// Each 32-lane half handles one edge per iteration with float4 row loads;
// no shuffles in the loop (edge weight is precomputed in the edge record).
// MODE 0: out[node] = relu(agg + bias)
// MODE 2: pool[batch[node]] += agg   (atomic; no bias, no relu)
template <int MODE>
__global__ __launch_bounds__(256) void k_agg(
        const float* __restrict__ Hin, const float* __restrict__ dinv,
        const int* __restrict__ row_ptr, const int2* __restrict__ edges,
        const float* __restrict__ bias, float* __restrict__ out,
        const int* __restrict__ batch, float* __restrict__ pool) {
    int wave = threadIdx.x >> 6, lane = threadIdx.x & 63;
    int half = lane >> 5, li = lane & 31;
    int node = blockIdx.x * 4 + wave;
    if (node >= N_NODES) return;

    float di = dinv[node];
    float4 acc = make_float4(0.f, 0.f, 0.f, 0.f);
    if (half == 0) {                     // self-loop term
        float4 v = ((const float4*)(Hin + (size_t)node * HDIM))[li];
        float w = di * di;
        acc.x = v.x * w; acc.y = v.y * w; acc.z = v.z * w; acc.w = v.w * w;
    }

    int rs = row_ptr[node], re = row_ptr[node + 1];
#pragma unroll 2
    for (int e = rs + half; e < re; e += 2) {
        int2 er = edges[e];              // 32-lane uniform load
        float w = __int_as_float(er.y);
        float4 v = ((const float4*)(Hin + (size_t)er.x * HDIM))[li];
        acc.x += v.x * w; acc.y += v.y * w; acc.z += v.z * w; acc.w += v.w * w;
    }

    acc.x += __shfl_xor(acc.x, 32);
    acc.y += __shfl_xor(acc.y, 32);
    acc.z += __shfl_xor(acc.z, 32);
    acc.w += __shfl_xor(acc.w, 32);

    if (half == 0) {
        if (MODE == 2) {
            int g = batch[node];
            float* p = pool + (size_t)g * HDIM + li * 4;
            atomicAdd(p + 0, acc.x); atomicAdd(p + 1, acc.y);
            atomicAdd(p + 2, acc.z); atomicAdd(p + 3, acc.w);
        } else {
            float4 b = ((const float4*)bias)[li];
            float4 o;
            o.x = fmaxf(acc.x + b.x, 0.f);
            o.y = fmaxf(acc.y + b.y, 0.f);
            o.z = fmaxf(acc.z + b.z, 0.f);
            o.w = fmaxf(acc.w + b.w, 0.f);
            ((float4*)(out + (size_t)node * HDIM))[li] = o;
        }
    }
}

// ---------------- divide pooled sums by graph node counts ------------------
__global__ void k_divpool(float* __restrict__ pool, const float* __restrict__ cnt_g) {
    int i = blockIdx.x * blockDim.x + threadIdx.x;
    if (i < NGRAPH * HDIM) pool[i] /= fmaxf(cnt_g[i >> 7], 1.0f);
}

extern "C" void kernel_launch(void* const* d_in, const int* in_sizes, int n_in,
                              void* d_out, int out_size, void* d_ws, size_t ws_size,
                              hipStream_t stream) {
    (void)in_sizes; (void)n_in; (void)out_size; (void)ws_size;

    const float* x[2]  = {(const float*)d_in[0], (const float*)d_in[1]};
    const int*   ei[2] = {(const int*)d_in[2], (const int*)d_in[3]};
    const int*   bt[2] = {(const int*)d_in[4], (const int*)d_in[5]};
    const float* W1  = (const float*)d_in[6];  const float* b1  = (const float*)d_in[7];
    const float* W2  = (const float*)d_in[8];  const float* b2  = (const float*)d_in[9];
    const float* W3  = (const float*)d_in[10]; const float* b3  = (const float*)d_in[11];
    const float* Wc1 = (const float*)d_in[12]; const float* bc1 = (const float*)d_in[13];
    const float* Wc2 = (const float*)d_in[14]; const float* bc2 = (const float*)d_in[15];
    const float* Wc3 = (const float*)d_in[16]; const float* bc3 = (const float*)d_in[17];
    float* out = (float*)d_out;

    char* ws = (char*)d_ws;
    size_t off = 0;
    auto carve = [&](size_t bytes) -> char* {
        char* p = ws + off;
        off += (bytes + 255) & ~(size_t)255;
        return p;
    };

    // contiguous zero-group (zeroed once per side with one launch)
    int*   edge_cnt = (int*)  carve((size_t)N_NODES * 4);
    int*   fill_cnt = (int*)  carve((size_t)N_NODES * 4);
    float* pool_s   = (float*)carve((size_t)NGRAPH * HDIM * 4);
    float* cnt_g    = (float*)carve((size_t)NGRAPH * 4);
    int zero_words = (int)(((char*)(cnt_g + NGRAPH) - (char*)edge_cnt + 3) / 4);

    float* dinv       = (float*)carve((size_t)N_NODES * 4);
    int*   row_ptr    = (int*)  carve((size_t)(N_NODES + 1) * 4);
    int2*  edges      = (int2*) carve((size_t)E_EDGES * 8);
    int*   blksum     = (int*)  carve(512 * 4);
    float* hA         = (float*)carve((size_t)N_NODES * HDIM * 4);
    float* hB         = (float*)carve((size_t)N_NODES * HDIM * 4);
    float* zcat       = (float*)carve((size_t)NGRAPH * 2 * HDIM * 4);
    float* z1         = (float*)carve((size_t)NGRAPH * 4 * HDIM * 4);
    float* z2         = (float*)carve((size_t)NGRAPH * 2 * HDIM * 4);

    const int nscan = (N_NODES + 511) / 512;             // 98 blocks
    const int gemm128_blocks = (N_NODES + 127) / 128;    // 391
    const int agg_blocks = (N_NODES + 3) / 4;            // 12500

    for (int s = 0; s < 2; ++s) {
        const int* esrc = ei[s];
        const int* edst = ei[s] + E_EDGES;

        k_zero<<<512, 256, 0, stream>>>(edge_cnt, zero_words);
        k_hist<<<512, 256, 0, stream>>>(edst, edge_cnt);
        k_scan_a<<<nscan, 512, 0, stream>>>(edge_cnt, row_ptr, blksum, dinv, bt[s], cnt_g);
        k_scan_b<<<1, 512, 0, stream>>>(blksum, nscan);
        k_scan_c<<<nscan, 512, 0, stream>>>(row_ptr, blksum);
        k_fill<<<512, 256, 0, stream>>>(esrc, edst, row_ptr, fill_cnt, dinv, edges);

        // layer 1: hB = relu(agg(x @ W1) + b1)
        k_gemm128<<<gemm128_blocks, 256, 0, stream>>>(x[s], W1, hA, N_NODES);
        k_agg<0><<<agg_blocks, 256, 0, stream>>>(hA, dinv, row_ptr, edges, b1, hB, nullptr, nullptr);

        // layer 2: hB = relu(agg(hB @ W2) + b2)
        k_gemm128<<<gemm128_blocks, 256, 0, stream>>>(hB, W2, hA, N_NODES);
        k_agg<0><<<agg_blocks, 256, 0, stream>>>(hA, dinv, row_ptr, edges, b2, hB, nullptr, nullptr);

        // layer 3 (reordered by linearity): pool = mean(agg(hB)); then @W3+b3
        k_agg<2><<<agg_blocks, 256, 0, stream>>>(hB, dinv, row_ptr, edges, nullptr, nullptr, bt[s], pool_s);
        k_divpool<<<(NGRAPH * HDIM + 255) / 256, 256, 0, stream>>>(pool_s, cnt_g);
        k_gemm<<<dim3(NGRAPH / 64, HDIM / 64), 256, 0, stream>>>(pool_s, W3, b3, zcat + s * HDIM,
                                                                 NGRAPH, HDIM, HDIM, 2 * HDIM, 0);
    }

    // MLP head
    k_gemm<<<dim3(NGRAPH / 64, (4 * HDIM) / 64), 256, 0, stream>>>(zcat, Wc1, bc1, z1, NGRAPH, 4 * HDIM, 2 * HDIM, 4 * HDIM, 1);
    k_gemm<<<dim3(NGRAPH / 64, (2 * HDIM) / 64), 256, 0, stream>>>(z1, Wc2, bc2, z2, NGRAPH, 2 * HDIM, 4 * HDIM, 2 * HDIM, 1);
    k_gemm<<<dim3(NGRAPH / 64, 1), 256, 0, stream>>>(z2, Wc3, bc3, out, NGRAPH, OUTC, 2 * HDIM, OUTC, 0);
}

// Round 3
// 862.852 us; speedup vs baseline: 1.1339x; 1.1339x over previous
//
#include <hip/hip_runtime.h>
#include <math.h>

#define N_NODES 50000
#define E_EDGES 500000
#define F_IN    128
#define HDIM    128
#define OUTC    2
#define NGRAPH  512

// ---------------- utility: zero a span of 4-byte words ----------------
__global__ void k_zero(int* __restrict__ p, int n) {
    int i = blockIdx.x * blockDim.x + threadIdx.x;
    int stride = gridDim.x * blockDim.x;
    for (; i < n; i += stride) p[i] = 0;
}

// ---------------- edge histogram over dst ----------------
__global__ void k_hist(const int* __restrict__ dst, int* __restrict__ cnt) {
    int i = blockIdx.x * blockDim.x + threadIdx.x;
    int stride = gridDim.x * blockDim.x;
    for (; i < E_EDGES; i += stride) atomicAdd(&cnt[dst[i]], 1);
}

// ---------------- scan stage A: per-block exclusive scan of edge counts ----
__global__ void k_scan_a(const int* __restrict__ cnt, int* __restrict__ excl,
                         int* __restrict__ blksum, float* __restrict__ dinv,
                         const int* __restrict__ batch, float* __restrict__ cnt_g) {
    __shared__ int s[512];
    int t = threadIdx.x;
    int i = blockIdx.x * 512 + t;
    int v = 0;
    if (i < N_NODES) {
        v = cnt[i];
        dinv[i] = 1.0f / sqrtf((float)(v + 1));
        atomicAdd(&cnt_g[batch[i]], 1.0f);
    }
    s[t] = v; __syncthreads();
    for (int off = 1; off < 512; off <<= 1) {
        int add = (t >= off) ? s[t - off] : 0;
        __syncthreads();
        s[t] += add;
        __syncthreads();
    }
    if (i < N_NODES) excl[i] = s[t] - v;     // exclusive within block
    if (t == 511) blksum[blockIdx.x] = s[511];
}

// ---------------- scan stage B: exclusive scan of block sums (single block) --
__global__ void k_scan_b(int* __restrict__ blksum, int nb) {
    __shared__ int s[512];
    int t = threadIdx.x;
    int v = (t < nb) ? blksum[t] : 0;
    s[t] = v; __syncthreads();
    for (int off = 1; off < 512; off <<= 1) {
        int add = (t >= off) ? s[t - off] : 0;
        __syncthreads();
        s[t] += add;
        __syncthreads();
    }
    if (t < nb) blksum[t] = s[t] - v;        // exclusive, in place
}

// ---------------- scan stage C: add block offsets, finalize row_ptr --------
__global__ void k_scan_c(int* __restrict__ excl, const int* __restrict__ blksum) {
    int t = threadIdx.x;
    int i = blockIdx.x * 512 + t;
    if (i < N_NODES) excl[i] += blksum[blockIdx.x];
    if (i == 0) excl[N_NODES] = E_EDGES;
}

// ---------------- CSR fill: scatter (src, weight) records grouped by dst ---
__global__ void k_fill(const int* __restrict__ src, const int* __restrict__ dst,
                       const int* __restrict__ row_ptr, int* __restrict__ fill_cnt,
                       const float* __restrict__ dinv, int2* __restrict__ edges) {
    int i = blockIdx.x * blockDim.x + threadIdx.x;
    int stride = gridDim.x * blockDim.x;
    for (; i < E_EDGES; i += stride) {
        int d = dst[i];
        int s = src[i];
        int p = atomicAdd(&fill_cnt[d], 1);
        float w = dinv[s] * dinv[d];
        edges[row_ptr[d] + p] = make_int2(s, __float_as_int(w));
    }
}

// ---------------- generic fp32 GEMM: C = act(A@B + bias) -------------------
// used for the small pool/head GEMMs only.
__global__ __launch_bounds__(256) void k_gemm(
        const float* __restrict__ A, const float* __restrict__ B,
        const float* __restrict__ bias, float* __restrict__ C,
        int M, int Nn, int K, int ldc, int act) {
    __shared__ float As[16][64];
    __shared__ float Bs[16][68];
    int tid = threadIdx.x;
    int tx = tid & 15, ty = tid >> 4;
    int row0 = blockIdx.x * 64, col0 = blockIdx.y * 64;
    float acc[4][4] = {};
    int arow = tid >> 2;
    int acol = (tid & 3) * 4;
    int brow = tid >> 4;
    int bcol = (tid & 15) * 4;

    for (int k0 = 0; k0 < K; k0 += 16) {
        float4 av = make_float4(0.f, 0.f, 0.f, 0.f);
        int ar = row0 + arow;
        if (ar < M) av = *(const float4*)(A + (size_t)ar * K + k0 + acol);
        As[acol + 0][arow] = av.x;
        As[acol + 1][arow] = av.y;
        As[acol + 2][arow] = av.z;
        As[acol + 3][arow] = av.w;

        float4 bv = make_float4(0.f, 0.f, 0.f, 0.f);
        const float* Brow = B + (size_t)(k0 + brow) * Nn;
        int bc = col0 + bcol;
        if (bc + 3 < Nn) {
            bv = *(const float4*)(Brow + bc);
        } else {
            if (bc     < Nn) bv.x = Brow[bc];
            if (bc + 1 < Nn) bv.y = Brow[bc + 1];
            if (bc + 2 < Nn) bv.z = Brow[bc + 2];
        }
        Bs[brow][bcol + 0] = bv.x;
        Bs[brow][bcol + 1] = bv.y;
        Bs[brow][bcol + 2] = bv.z;
        Bs[brow][bcol + 3] = bv.w;
        __syncthreads();

#pragma unroll
        for (int k = 0; k < 16; k++) {
            float4 a = *(const float4*)&As[k][ty * 4];
            float4 b = *(const float4*)&Bs[k][tx * 4];
            acc[0][0] += a.x * b.x; acc[0][1] += a.x * b.y; acc[0][2] += a.x * b.z; acc[0][3] += a.x * b.w;
            acc[1][0] += a.y * b.x; acc[1][1] += a.y * b.y; acc[1][2] += a.y * b.z; acc[1][3] += a.y * b.w;
            acc[2][0] += a.z * b.x; acc[2][1] += a.z * b.y; acc[2][2] += a.z * b.z; acc[2][3] += a.z * b.w;
            acc[3][0] += a.w * b.x; acc[3][1] += a.w * b.y; acc[3][2] += a.w * b.z; acc[3][3] += a.w * b.w;
        }
        __syncthreads();
    }

#pragma unroll
    for (int i = 0; i < 4; i++) {
        int r = row0 + ty * 4 + i;
        if (r >= M) continue;
#pragma unroll
        for (int j = 0; j < 4; j++) {
            int c = col0 + tx * 4 + j;
            if (c >= Nn) continue;
            float v = acc[i][j];
            if (bias) v += bias[c];
            if (act) v = fmaxf(v, 0.0f);
            C[(size_t)r * ldc + c] = v;
        }
    }
}

// ---------------- specialized fp32 GEMM for N=K=128 (node-feature layers) --
// 128x128 block tile, 8x8 micro-tile, BK=16. C = A@B (no bias/act; those are
// fused into k_agg).
__global__ __launch_bounds__(256) void k_gemm128(
        const float* __restrict__ A, const float* __restrict__ Bg,
        float* __restrict__ C, int M) {
    __shared__ float As[16][128];
    __shared__ float Bs[16 * 128];
    int tid = threadIdx.x;
    int tx = tid & 15, ty = tid >> 4;
    int row0 = blockIdx.x * 128;
    float acc[8][8] = {};

    int arow = tid >> 1;                // 0..127
    int akc  = (tid & 1) * 8;           // 0 or 8
    const float* Aptr = A + (size_t)(row0 + arow) * 128 + akc;
    bool aok = (row0 + arow) < M;
    const float4* Bv = (const float4*)Bg;
    float4* Bsv = (float4*)Bs;

    for (int k0 = 0; k0 < 128; k0 += 16) {
        float4 a0 = make_float4(0.f, 0.f, 0.f, 0.f), a1 = a0;
        if (aok) {
            a0 = *(const float4*)(Aptr + k0);
            a1 = *(const float4*)(Aptr + k0 + 4);
        }
        float4 b0 = Bv[k0 * 32 + tid];
        float4 b1 = Bv[k0 * 32 + tid + 256];
        __syncthreads();                // previous-iter LDS readers done
        As[akc + 0][arow] = a0.x; As[akc + 1][arow] = a0.y;
        As[akc + 2][arow] = a0.z; As[akc + 3][arow] = a0.w;
        As[akc + 4][arow] = a1.x; As[akc + 5][arow] = a1.y;
        As[akc + 6][arow] = a1.z; As[akc + 7][arow] = a1.w;
        Bsv[tid] = b0;
        Bsv[tid + 256] = b1;
        __syncthreads();
#pragma unroll
        for (int k = 0; k < 16; k++) {
            float4 am0 = *(const float4*)&As[k][ty * 8];
            float4 am1 = *(const float4*)&As[k][ty * 8 + 4];
            float4 bn0 = *(const float4*)&Bs[k * 128 + tx * 4];
            float4 bn1 = *(const float4*)&Bs[k * 128 + 64 + tx * 4];
            float am[8] = {am0.x, am0.y, am0.z, am0.w, am1.x, am1.y, am1.z, am1.w};
            float bn[8] = {bn0.x, bn0.y, bn0.z, bn0.w, bn1.x, bn1.y, bn1.z, bn1.w};
#pragma unroll
            for (int i = 0; i < 8; i++)
#pragma unroll
                for (int j = 0; j < 8; j++)
                    acc[i][j] += am[i] * bn[j];
        }
    }

#pragma unroll
    for (int i = 0; i < 8; i++) {
        int r = row0 + ty * 8 + i;
        if (r >= M) continue;
        *(float4*)(C + (size_t)r * 128 + tx * 4) =
            make_float4(acc[i][0], acc[i][1], acc[i][2], acc[i][3]);
        *(float4*)(C + (size_t)r * 128 + 64 + tx * 4) =
            make_float4(acc[i][4], acc[i][5], acc[i][6], acc[i][7]);
    }
}

// ---------------- CSR aggregation (wave per node, float2 per lane) ---------
// Edge records (src, precomputed weight) are loaded 64-at-a-time coalesced
// into registers; the inner loop broadcasts FOUR edges per iteration via
// independent shuffles, then issues FOUR independent 512B row-gathers before
// any dependent FMA -> 4 loads in flight per wave (latency hiding).
// MODE 0: out[node] = relu(agg + bias)
// MODE 2: pool[batch[node]] += agg   (atomic; no bias, no relu)
template <int MODE>
__global__ __launch_bounds__(256) void k_agg(
        const float* __restrict__ Hin, const float* __restrict__ dinv,
        const int* __restrict__ row_ptr, const int2* __restrict__ edges,
        const float* __restrict__ bias, float* __restrict__ out,
        const int* __restrict__ batch, float* __restrict__ pool) {
    int wave = threadIdx.x >> 6, lane = threadIdx.x & 63;
    int node = blockIdx.x * 4 + wave;
    if (node >= N_NODES) return;

    float di = dinv[node];
    float2 hv = ((const float2*)(Hin + (size_t)node * HDIM))[lane];
    float wself = di * di;
    float ax = hv.x * wself;
    float ay = hv.y * wself;

    int rs = row_ptr[node], re = row_ptr[node + 1];
    for (int base = rs; base < re; base += 64) {
        int e = base + lane;
        int s = 0; float w = 0.f;
        if (e < re) {
            int2 er = edges[e];
            s = er.x;
            w = __int_as_float(er.y);
        }
        int cnt = re - base; if (cnt > 64) cnt = 64;
        int j = 0;
        for (; j + 4 <= cnt; j += 4) {
            int   s0 = __shfl(s, j + 0), s1 = __shfl(s, j + 1);
            int   s2 = __shfl(s, j + 2), s3 = __shfl(s, j + 3);
            float q0 = __shfl(w, j + 0), q1 = __shfl(w, j + 1);
            float q2 = __shfl(w, j + 2), q3 = __shfl(w, j + 3);
            float2 v0 = ((const float2*)(Hin + (size_t)s0 * HDIM))[lane];
            float2 v1 = ((const float2*)(Hin + (size_t)s1 * HDIM))[lane];
            float2 v2 = ((const float2*)(Hin + (size_t)s2 * HDIM))[lane];
            float2 v3 = ((const float2*)(Hin + (size_t)s3 * HDIM))[lane];
            ax += v0.x * q0; ay += v0.y * q0;
            ax += v1.x * q1; ay += v1.y * q1;
            ax += v2.x * q2; ay += v2.y * q2;
            ax += v3.x * q3; ay += v3.y * q3;
        }
        for (; j < cnt; j++) {
            int   sj = __shfl(s, j);
            float qj = __shfl(w, j);
            float2 v = ((const float2*)(Hin + (size_t)sj * HDIM))[lane];
            ax += v.x * qj; ay += v.y * qj;
        }
    }

    if (MODE == 2) {
        int g = batch[node];
        atomicAdd(pool + (size_t)g * HDIM + lane * 2,     ax);
        atomicAdd(pool + (size_t)g * HDIM + lane * 2 + 1, ay);
    } else {
        float ox = fmaxf(ax + bias[lane * 2],     0.0f);
        float oy = fmaxf(ay + bias[lane * 2 + 1], 0.0f);
        ((float2*)(out + (size_t)node * HDIM))[lane] = make_float2(ox, oy);
    }
}

// ---------------- divide pooled sums by graph node counts ------------------
__global__ void k_divpool(float* __restrict__ pool, const float* __restrict__ cnt_g) {
    int i = blockIdx.x * blockDim.x + threadIdx.x;
    if (i < NGRAPH * HDIM) pool[i] /= fmaxf(cnt_g[i >> 7], 1.0f);
}

extern "C" void kernel_launch(void* const* d_in, const int* in_sizes, int n_in,
                              void* d_out, int out_size, void* d_ws, size_t ws_size,
                              hipStream_t stream) {
    (void)in_sizes; (void)n_in; (void)out_size; (void)ws_size;

    const float* x[2]  = {(const float*)d_in[0], (const float*)d_in[1]};
    const int*   ei[2] = {(const int*)d_in[2], (const int*)d_in[3]};
    const int*   bt[2] = {(const int*)d_in[4], (const int*)d_in[5]};
    const float* W1  = (const float*)d_in[6];  const float* b1  = (const float*)d_in[7];
    const float* W2  = (const float*)d_in[8];  const float* b2  = (const float*)d_in[9];
    const float* W3  = (const float*)d_in[10]; const float* b3  = (const float*)d_in[11];
    const float* Wc1 = (const float*)d_in[12]; const float* bc1 = (const float*)d_in[13];
    const float* Wc2 = (const float*)d_in[14]; const float* bc2 = (const float*)d_in[15];
    const float* Wc3 = (const float*)d_in[16]; const float* bc3 = (const float*)d_in[17];
    float* out = (float*)d_out;

    char* ws = (char*)d_ws;
    size_t off = 0;
    auto carve = [&](size_t bytes) -> char* {
        char* p = ws + off;
        off += (bytes + 255) & ~(size_t)255;
        return p;
    };

    // contiguous zero-group (zeroed once per side with one launch)
    int*   edge_cnt = (int*)  carve((size_t)N_NODES * 4);
    int*   fill_cnt = (int*)  carve((size_t)N_NODES * 4);
    float* pool_s   = (float*)carve((size_t)NGRAPH * HDIM * 4);
    float* cnt_g    = (float*)carve((size_t)NGRAPH * 4);
    int zero_words = (int)(((char*)(cnt_g + NGRAPH) - (char*)edge_cnt + 3) / 4);

    float* dinv       = (float*)carve((size_t)N_NODES * 4);
    int*   row_ptr    = (int*)  carve((size_t)(N_NODES + 1) * 4);
    int2*  edges      = (int2*) carve((size_t)E_EDGES * 8);
    int*   blksum     = (int*)  carve(512 * 4);
    float* hA         = (float*)carve((size_t)N_NODES * HDIM * 4);
    float* hB         = (float*)carve((size_t)N_NODES * HDIM * 4);
    float* zcat       = (float*)carve((size_t)NGRAPH * 2 * HDIM * 4);
    float* z1         = (float*)carve((size_t)NGRAPH * 4 * HDIM * 4);
    float* z2         = (float*)carve((size_t)NGRAPH * 2 * HDIM * 4);

    const int nscan = (N_NODES + 511) / 512;             // 98 blocks
    const int gemm128_blocks = (N_NODES + 127) / 128;    // 391
    const int agg_blocks = (N_NODES + 3) / 4;            // 12500

    for (int s = 0; s < 2; ++s) {
        const int* esrc = ei[s];
        const int* edst = ei[s] + E_EDGES;

        k_zero<<<512, 256, 0, stream>>>(edge_cnt, zero_words);
        k_hist<<<512, 256, 0, stream>>>(edst, edge_cnt);
        k_scan_a<<<nscan, 512, 0, stream>>>(edge_cnt, row_ptr, blksum, dinv, bt[s], cnt_g);
        k_scan_b<<<1, 512, 0, stream>>>(blksum, nscan);
        k_scan_c<<<nscan, 512, 0, stream>>>(row_ptr, blksum);
        k_fill<<<512, 256, 0, stream>>>(esrc, edst, row_ptr, fill_cnt, dinv, edges);

        // layer 1: hB = relu(agg(x @ W1) + b1)
        k_gemm128<<<gemm128_blocks, 256, 0, stream>>>(x[s], W1, hA, N_NODES);
        k_agg<0><<<agg_blocks, 256, 0, stream>>>(hA, dinv, row_ptr, edges, b1, hB, nullptr, nullptr);

        // layer 2: hB = relu(agg(hB @ W2) + b2)
        k_gemm128<<<gemm128_blocks, 256, 0, stream>>>(hB, W2, hA, N_NODES);
        k_agg<0><<<agg_blocks, 256, 0, stream>>>(hA, dinv, row_ptr, edges, b2, hB, nullptr, nullptr);

        // layer 3 (reordered by linearity): pool = mean(agg(hB)); then @W3+b3
        k_agg<2><<<agg_blocks, 256, 0, stream>>>(hB, dinv, row_ptr, edges, nullptr, nullptr, bt[s], pool_s);
        k_divpool<<<(NGRAPH * HDIM + 255) / 256, 256, 0, stream>>>(pool_s, cnt_g);
        k_gemm<<<dim3(NGRAPH / 64, HDIM / 64), 256, 0, stream>>>(pool_s, W3, b3, zcat + s * HDIM,
                                                                 NGRAPH, HDIM, HDIM, 2 * HDIM, 0);
    }

    // MLP head
    k_gemm<<<dim3(NGRAPH / 64, (4 * HDIM) / 64), 256, 0, stream>>>(zcat, Wc1, bc1, z1, NGRAPH, 4 * HDIM, 2 * HDIM, 4 * HDIM, 1);
    k_gemm<<<dim3(NGRAPH / 64, (2 * HDIM) / 64), 256, 0, stream>>>(z1, Wc2, bc2, z2, NGRAPH, 2 * HDIM, 4 * HDIM, 2 * HDIM, 1);
    k_gemm<<<dim3(NGRAPH / 64, 1), 256, 0, stream>>>(z2, Wc3, bc3, out, NGRAPH, OUTC, 2 * HDIM, OUTC, 0);
}

// Round 4
// 768.496 us; speedup vs baseline: 1.2731x; 1.1228x over previous
//
#include <hip/hip_runtime.h>
#include <math.h>

#define N_NODES 50000
#define E_EDGES 500000
#define HDIM    128
#define OUTC    2
#define NGRAPH  512

// ---------------- utility: zero a span of 4-byte words ----------------
__global__ void k_zero(int* __restrict__ p, int n) {
    int i = blockIdx.x * blockDim.x + threadIdx.x;
    int stride = gridDim.x * blockDim.x;
    for (; i < n; i += stride) p[i] = 0;
}

// ---------------- edge histogram over dst (1 or 2 sides) -------------------
// i < E_EDGES -> side 0 (d0), else side 1 (d1, node ids offset by off1).
__global__ void k_hist(const int* __restrict__ d0, const int* __restrict__ d1,
                       int ecnt, int off1, int* __restrict__ cnt) {
    int i = blockIdx.x * blockDim.x + threadIdx.x;
    int stride = gridDim.x * blockDim.x;
    for (; i < ecnt; i += stride) {
        int d = (i < E_EDGES) ? d0[i] : d1[i - E_EDGES] + off1;
        atomicAdd(&cnt[d], 1);
    }
}

// ---------------- scan stage A: per-block exclusive scan of edge counts ----
// also computes dinv and per-graph node counts.
__global__ void k_scan_a(const int* __restrict__ cnt, int* __restrict__ excl,
                         int* __restrict__ blksum, float* __restrict__ dinv,
                         const int* __restrict__ bt0, const int* __restrict__ bt1,
                         int goff0, int nn, int nside, float* __restrict__ cnt_g) {
    __shared__ int s[512];
    int t = threadIdx.x;
    int i = blockIdx.x * 512 + t;
    int v = 0;
    if (i < nn) {
        v = cnt[i];
        dinv[i] = 1.0f / sqrtf((float)(v + 1));
        int g = (i < nside) ? bt0[i] + goff0 : bt1[i - nside] + NGRAPH;
        atomicAdd(&cnt_g[g], 1.0f);
    }
    s[t] = v; __syncthreads();
    for (int off = 1; off < 512; off <<= 1) {
        int add = (t >= off) ? s[t - off] : 0;
        __syncthreads();
        s[t] += add;
        __syncthreads();
    }
    if (i < nn) excl[i] = s[t] - v;
    if (t == 511) blksum[blockIdx.x] = s[511];
}

// ---------------- scan stage B: exclusive scan of block sums ---------------
__global__ void k_scan_b(int* __restrict__ blksum, int nb) {
    __shared__ int s[512];
    int t = threadIdx.x;
    int v = (t < nb) ? blksum[t] : 0;
    s[t] = v; __syncthreads();
    for (int off = 1; off < 512; off <<= 1) {
        int add = (t >= off) ? s[t - off] : 0;
        __syncthreads();
        s[t] += add;
        __syncthreads();
    }
    if (t < nb) blksum[t] = s[t] - v;
}

// ---------------- scan stage C: add block offsets, finalize row_ptr --------
__global__ void k_scan_c(int* __restrict__ excl, const int* __restrict__ blksum,
                         int nn, int tot) {
    int t = threadIdx.x;
    int i = blockIdx.x * 512 + t;
    if (i < nn) excl[i] += blksum[blockIdx.x];
    if (i == 0) excl[nn] = tot;
}

// ---------------- CSR fill: scatter (local src, weight) grouped by dst -----
__global__ void k_fill(const int* __restrict__ s0, const int* __restrict__ s1,
                       const int* __restrict__ d0, const int* __restrict__ d1,
                       int ecnt, int off1,
                       const int* __restrict__ row_ptr, int* __restrict__ fill_cnt,
                       const float* __restrict__ dinv, int2* __restrict__ edges) {
    int i = blockIdx.x * blockDim.x + threadIdx.x;
    int stride = gridDim.x * blockDim.x;
    for (; i < ecnt; i += stride) {
        int sl, d, sg;
        if (i < E_EDGES) { sl = s0[i]; d = d0[i]; sg = sl; }
        else             { sl = s1[i - E_EDGES]; d = d1[i - E_EDGES] + off1; sg = sl + off1; }
        int p = atomicAdd(&fill_cnt[d], 1);
        float w = dinv[sg] * dinv[d];
        edges[row_ptr[d] + p] = make_int2(sl, __float_as_int(w));
    }
}

// ---------------- generic fp32 GEMM: C = act(A@B + bias) -------------------
__global__ __launch_bounds__(256) void k_gemm(
        const float* __restrict__ A, const float* __restrict__ B,
        const float* __restrict__ bias, float* __restrict__ C,
        int M, int Nn, int K, int ldc, int act) {
    __shared__ float As[16][64];
    __shared__ float Bs[16][68];
    int tid = threadIdx.x;
    int tx = tid & 15, ty = tid >> 4;
    int row0 = blockIdx.x * 64, col0 = blockIdx.y * 64;
    float acc[4][4] = {};
    int arow = tid >> 2;
    int acol = (tid & 3) * 4;
    int brow = tid >> 4;
    int bcol = (tid & 15) * 4;

    for (int k0 = 0; k0 < K; k0 += 16) {
        float4 av = make_float4(0.f, 0.f, 0.f, 0.f);
        int ar = row0 + arow;
        if (ar < M) av = *(const float4*)(A + (size_t)ar * K + k0 + acol);
        As[acol + 0][arow] = av.x;
        As[acol + 1][arow] = av.y;
        As[acol + 2][arow] = av.z;
        As[acol + 3][arow] = av.w;

        float4 bv = make_float4(0.f, 0.f, 0.f, 0.f);
        const float* Brow = B + (size_t)(k0 + brow) * Nn;
        int bc = col0 + bcol;
        if (bc + 3 < Nn) {
            bv = *(const float4*)(Brow + bc);
        } else {
            if (bc     < Nn) bv.x = Brow[bc];
            if (bc + 1 < Nn) bv.y = Brow[bc + 1];
            if (bc + 2 < Nn) bv.z = Brow[bc + 2];
        }
        Bs[brow][bcol + 0] = bv.x;
        Bs[brow][bcol + 1] = bv.y;
        Bs[brow][bcol + 2] = bv.z;
        Bs[brow][bcol + 3] = bv.w;
        __syncthreads();

#pragma unroll
        for (int k = 0; k < 16; k++) {
            float4 a = *(const float4*)&As[k][ty * 4];
            float4 b = *(const float4*)&Bs[k][tx * 4];
            acc[0][0] += a.x * b.x; acc[0][1] += a.x * b.y; acc[0][2] += a.x * b.z; acc[0][3] += a.x * b.w;
            acc[1][0] += a.y * b.x; acc[1][1] += a.y * b.y; acc[1][2] += a.y * b.z; acc[1][3] += a.y * b.w;
            acc[2][0] += a.z * b.x; acc[2][1] += a.z * b.y; acc[2][2] += a.z * b.z; acc[2][3] += a.z * b.w;
            acc[3][0] += a.w * b.x; acc[3][1] += a.w * b.y; acc[3][2] += a.w * b.z; acc[3][3] += a.w * b.w;
        }
        __syncthreads();
    }

#pragma unroll
    for (int i = 0; i < 4; i++) {
        int r = row0 + ty * 4 + i;
        if (r >= M) continue;
#pragma unroll
        for (int j = 0; j < 4; j++) {
            int c = col0 + tx * 4 + j;
            if (c >= Nn) continue;
            float v = acc[i][j];
            if (bias) v += bias[c];
            if (act) v = fmaxf(v, 0.0f);
            C[(size_t)r * ldc + c] = v;
        }
    }
}

// ---------------- specialized fp32 GEMM, N=K=128, dual-A-base --------------
// row r takes its A row from A0 (r < nside) or A1 (r - nside). C contiguous.
__global__ __launch_bounds__(256) void k_gemm128(
        const float* __restrict__ A0, const float* __restrict__ A1,
        const float* __restrict__ Bg, float* __restrict__ C,
        int M, int nside) {
    __shared__ float As[16][128];
    __shared__ float Bs[16 * 128];
    int tid = threadIdx.x;
    int tx = tid & 15, ty = tid >> 4;
    int row0 = blockIdx.x * 128;
    float acc[8][8] = {};

    int arow = tid >> 1;                // 0..127
    int akc  = (tid & 1) * 8;           // 0 or 8
    int r = row0 + arow;
    bool aok = r < M;
    const float* Ab = (r < nside) ? A0 + (size_t)r * 128
                                  : A1 + (size_t)(r - nside) * 128;
    const float* Aptr = Ab + akc;
    const float4* Bv = (const float4*)Bg;
    float4* Bsv = (float4*)Bs;

    for (int k0 = 0; k0 < 128; k0 += 16) {
        float4 a0 = make_float4(0.f, 0.f, 0.f, 0.f), a1 = a0;
        if (aok) {
            a0 = *(const float4*)(Aptr + k0);
            a1 = *(const float4*)(Aptr + k0 + 4);
        }
        float4 b0 = Bv[k0 * 32 + tid];
        float4 b1 = Bv[k0 * 32 + tid + 256];
        __syncthreads();
        As[akc + 0][arow] = a0.x; As[akc + 1][arow] = a0.y;
        As[akc + 2][arow] = a0.z; As[akc + 3][arow] = a0.w;
        As[akc + 4][arow] = a1.x; As[akc + 5][arow] = a1.y;
        As[akc + 6][arow] = a1.z; As[akc + 7][arow] = a1.w;
        Bsv[tid] = b0;
        Bsv[tid + 256] = b1;
        __syncthreads();
#pragma unroll
        for (int k = 0; k < 16; k++) {
            float4 am0 = *(const float4*)&As[k][ty * 8];
            float4 am1 = *(const float4*)&As[k][ty * 8 + 4];
            float4 bn0 = *(const float4*)&Bs[k * 128 + tx * 4];
            float4 bn1 = *(const float4*)&Bs[k * 128 + 64 + tx * 4];
            float am[8] = {am0.x, am0.y, am0.z, am0.w, am1.x, am1.y, am1.z, am1.w};
            float bn[8] = {bn0.x, bn0.y, bn0.z, bn0.w, bn1.x, bn1.y, bn1.z, bn1.w};
#pragma unroll
            for (int i = 0; i < 8; i++)
#pragma unroll
                for (int j = 0; j < 8; j++)
                    acc[i][j] += am[i] * bn[j];
        }
    }

#pragma unroll
    for (int i = 0; i < 8; i++) {
        int rr = row0 + ty * 8 + i;
        if (rr >= M) continue;
        *(float4*)(C + (size_t)rr * 128 + tx * 4) =
            make_float4(acc[i][0], acc[i][1], acc[i][2], acc[i][3]);
        *(float4*)(C + (size_t)rr * 128 + 64 + tx * 4) =
            make_float4(acc[i][4], acc[i][5], acc[i][6], acc[i][7]);
    }
}

// ---------------- CSR aggregation: scalar edge metadata, 8 gathers in flight
// One wave per node. Edge index/weight are wave-uniform -> forced into SGPRs
// via readfirstlane so edge-record reads become s_load and row addresses are
// SGPR-base + lane-offset. 8 independent 512B row gathers issue per iter;
// tail slots clamp to the last valid edge (L1-hit duplicate) with weight 0.
// MODE 0: out[node] = relu(agg + bias);  MODE 2: pool[gid] += agg (atomic).
template <int MODE>
__global__ __launch_bounds__(256) void k_agg(
        const float* __restrict__ H0, const float* __restrict__ H1,
        const float* __restrict__ dinv, const int* __restrict__ row_ptr,
        const int2* __restrict__ edges, const float* __restrict__ bias,
        float* __restrict__ out0, float* __restrict__ out1,
        const int* __restrict__ bt0, const int* __restrict__ bt1,
        int goff0, int nnodes, int nside, float* __restrict__ pool) {
    int wave = threadIdx.x >> 6, lane = threadIdx.x & 63;
    int node = blockIdx.x * 4 + wave;
    if (node >= nnodes) return;
    int side = node >= nside;
    int nl = side ? node - nside : node;
    const float* H = side ? H1 : H0;

    float di = dinv[node];
    float2 hv = ((const float2*)(H + (size_t)nl * HDIM))[lane];
    float wself = di * di;
    float ax = hv.x * wself;
    float ay = hv.y * wself;

    int rs = __builtin_amdgcn_readfirstlane(row_ptr[node]);
    int re = __builtin_amdgcn_readfirstlane(row_ptr[node + 1]);
    for (int base = rs; base < re; base += 8) {
        int nrem = re - base;                // uniform, >= 1
        int m = nrem - 1;
        int i1 = 1 < nrem ? 1 : m;
        int i2 = 2 < nrem ? 2 : m;
        int i3 = 3 < nrem ? 3 : m;
        int i4 = 4 < nrem ? 4 : m;
        int i5 = 5 < nrem ? 5 : m;
        int i6 = 6 < nrem ? 6 : m;
        int i7 = 7 < nrem ? 7 : m;
        int2 E0 = edges[base];
        int2 E1 = edges[base + i1];
        int2 E2 = edges[base + i2];
        int2 E3 = edges[base + i3];
        int2 E4 = edges[base + i4];
        int2 E5 = edges[base + i5];
        int2 E6 = edges[base + i6];
        int2 E7 = edges[base + i7];
        float2 v0 = ((const float2*)(H + (size_t)E0.x * HDIM))[lane];
        float2 v1 = ((const float2*)(H + (size_t)E1.x * HDIM))[lane];
        float2 v2 = ((const float2*)(H + (size_t)E2.x * HDIM))[lane];
        float2 v3 = ((const float2*)(H + (size_t)E3.x * HDIM))[lane];
        float2 v4 = ((const float2*)(H + (size_t)E4.x * HDIM))[lane];
        float2 v5 = ((const float2*)(H + (size_t)E5.x * HDIM))[lane];
        float2 v6 = ((const float2*)(H + (size_t)E6.x * HDIM))[lane];
        float2 v7 = ((const float2*)(H + (size_t)E7.x * HDIM))[lane];
        float w0 = __int_as_float(E0.y);
        float w1 = 1 < nrem ? __int_as_float(E1.y) : 0.f;
        float w2 = 2 < nrem ? __int_as_float(E2.y) : 0.f;
        float w3 = 3 < nrem ? __int_as_float(E3.y) : 0.f;
        float w4 = 4 < nrem ? __int_as_float(E4.y) : 0.f;
        float w5 = 5 < nrem ? __int_as_float(E5.y) : 0.f;
        float w6 = 6 < nrem ? __int_as_float(E6.y) : 0.f;
        float w7 = 7 < nrem ? __int_as_float(E7.y) : 0.f;
        ax = fmaf(v0.x, w0, ax); ay = fmaf(v0.y, w0, ay);
        ax = fmaf(v1.x, w1, ax); ay = fmaf(v1.y, w1, ay);
        ax = fmaf(v2.x, w2, ax); ay = fmaf(v2.y, w2, ay);
        ax = fmaf(v3.x, w3, ax); ay = fmaf(v3.y, w3, ay);
        ax = fmaf(v4.x, w4, ax); ay = fmaf(v4.y, w4, ay);
        ax = fmaf(v5.x, w5, ax); ay = fmaf(v5.y, w5, ay);
        ax = fmaf(v6.x, w6, ax); ay = fmaf(v6.y, w6, ay);
        ax = fmaf(v7.x, w7, ax); ay = fmaf(v7.y, w7, ay);
    }

    if (MODE == 2) {
        int g = side ? bt1[nl] + NGRAPH : bt0[nl] + goff0;
        float* p = pool + (size_t)g * HDIM + lane * 2;
        atomicAdd(p,     ax);
        atomicAdd(p + 1, ay);
    } else {
        float ox = fmaxf(ax + bias[lane * 2],     0.0f);
        float oy = fmaxf(ay + bias[lane * 2 + 1], 0.0f);
        float* O = side ? out1 : out0;
        ((float2*)(O + (size_t)nl * HDIM))[lane] = make_float2(ox, oy);
    }
}

// ---------------- divide pooled sums by graph node counts ------------------
__global__ void k_divpool(float* __restrict__ pool, const float* __restrict__ cnt_g) {
    int i = blockIdx.x * blockDim.x + threadIdx.x;
    if (i < 2 * NGRAPH * HDIM) pool[i] /= fmaxf(cnt_g[i >> 7], 1.0f);
}

extern "C" void kernel_launch(void* const* d_in, const int* in_sizes, int n_in,
                              void* d_out, int out_size, void* d_ws, size_t ws_size,
                              hipStream_t stream) {
    (void)in_sizes; (void)n_in; (void)out_size;

    const float* x[2]  = {(const float*)d_in[0], (const float*)d_in[1]};
    const int*   ei[2] = {(const int*)d_in[2], (const int*)d_in[3]};
    const int*   bt[2] = {(const int*)d_in[4], (const int*)d_in[5]};
    const float* W1  = (const float*)d_in[6];  const float* b1  = (const float*)d_in[7];
    const float* W2  = (const float*)d_in[8];  const float* b2  = (const float*)d_in[9];
    const float* W3  = (const float*)d_in[10]; const float* b3  = (const float*)d_in[11];
    const float* Wc1 = (const float*)d_in[12]; const float* bc1 = (const float*)d_in[13];
    const float* Wc2 = (const float*)d_in[14]; const float* bc2 = (const float*)d_in[15];
    const float* Wc3 = (const float*)d_in[16]; const float* bc3 = (const float*)d_in[17];
    float* out = (float*)d_out;

    // batched path needs ~115 MB of workspace; otherwise per-side sequential
    // (same ~59 MB footprint as the previous passing round).
    const bool batched = ws_size >= 120ull * 1000 * 1000;
    const int NN = batched ? 2 * N_NODES : N_NODES;   // node-count of CSR build
    const int NE = batched ? 2 * E_EDGES : E_EDGES;   // edge-count of CSR build

    char* ws = (char*)d_ws;
    size_t off = 0;
    auto carve = [&](size_t bytes) -> char* {
        char* p = ws + off;
        off += (bytes + 255) & ~(size_t)255;
        return p;
    };

    int*   edge_cnt = (int*)  carve((size_t)NN * 4);
    int*   fill_cnt = (int*)  carve((size_t)NN * 4);
    float* pool_s   = (float*)carve((size_t)2 * NGRAPH * HDIM * 4);
    float* cnt_g    = (float*)carve((size_t)2 * NGRAPH * 4);
    float* dinv     = (float*)carve((size_t)NN * 4);
    int*   row_ptr  = (int*)  carve((size_t)(NN + 1) * 4);
    int2*  edges    = (int2*) carve((size_t)NE * 8);
    int*   blksum   = (int*)  carve(1024 * 4);
    float* hA       = (float*)carve((size_t)NN * HDIM * 4);
    float* hB       = (float*)carve((size_t)NN * HDIM * 4);
    float* zcat     = (float*)carve((size_t)NGRAPH * 2 * HDIM * 4);
    float* z1       = (float*)carve((size_t)NGRAPH * 4 * HDIM * 4);
    float* z2       = (float*)carve((size_t)NGRAPH * 2 * HDIM * 4);

    int zeroA_words = (int)(((char*)pool_s - (char*)edge_cnt) / 4); // cnt+fill
    int zeroB_words = (int)(((char*)dinv   - (char*)pool_s)   / 4); // pool+cnt_g

    // pool accumulators zeroed once
    k_zero<<<256, 256, 0, stream>>>((int*)pool_s, zeroB_words);

    if (batched) {
        const int nscan = (2 * N_NODES + 511) / 512;          // 196
        const int gblk  = (2 * N_NODES + 127) / 128;          // 782
        const int ablk  = (2 * N_NODES + 3) / 4;              // 25000

        k_zero<<<512, 256, 0, stream>>>(edge_cnt, zeroA_words);
        k_hist<<<1024, 256, 0, stream>>>(ei[0] + E_EDGES, ei[1] + E_EDGES,
                                         2 * E_EDGES, N_NODES, edge_cnt);
        k_scan_a<<<nscan, 512, 0, stream>>>(edge_cnt, row_ptr, blksum, dinv,
                                            bt[0], bt[1], 0, 2 * N_NODES, N_NODES, cnt_g);
        k_scan_b<<<1, 512, 0, stream>>>(blksum, nscan);
        k_scan_c<<<nscan, 512, 0, stream>>>(row_ptr, blksum, 2 * N_NODES, 2 * E_EDGES);
        k_fill<<<1024, 256, 0, stream>>>(ei[0], ei[1], ei[0] + E_EDGES, ei[1] + E_EDGES,
                                         2 * E_EDGES, N_NODES, row_ptr, fill_cnt, dinv, edges);

        float* hA1 = hA + (size_t)N_NODES * HDIM;
        float* hB1 = hB + (size_t)N_NODES * HDIM;

        k_gemm128<<<gblk, 256, 0, stream>>>(x[0], x[1], W1, hA, 2 * N_NODES, N_NODES);
        k_agg<0><<<ablk, 256, 0, stream>>>(hA, hA1, dinv, row_ptr, edges, b1,
                                           hB, hB1, bt[0], bt[1], 0, 2 * N_NODES, N_NODES, nullptr);
        k_gemm128<<<gblk, 256, 0, stream>>>(hB, hB1, W2, hA, 2 * N_NODES, N_NODES);
        k_agg<0><<<ablk, 256, 0, stream>>>(hA, hA1, dinv, row_ptr, edges, b2,
                                           hB, hB1, bt[0], bt[1], 0, 2 * N_NODES, N_NODES, nullptr);
        k_agg<2><<<ablk, 256, 0, stream>>>(hB, hB1, dinv, row_ptr, edges, nullptr,
                                           nullptr, nullptr, bt[0], bt[1], 0,
                                           2 * N_NODES, N_NODES, pool_s);
    } else {
        const int nscan = (N_NODES + 511) / 512;              // 98
        const int gblk  = (N_NODES + 127) / 128;              // 391
        const int ablk  = (N_NODES + 3) / 4;                  // 12500

        for (int s = 0; s < 2; ++s) {
            const int* esrc = ei[s];
            const int* edst = ei[s] + E_EDGES;
            int goff = s * NGRAPH;

            k_zero<<<512, 256, 0, stream>>>(edge_cnt, zeroA_words);
            k_hist<<<512, 256, 0, stream>>>(edst, edst, E_EDGES, 0, edge_cnt);
            k_scan_a<<<nscan, 512, 0, stream>>>(edge_cnt, row_ptr, blksum, dinv,
                                                bt[s], bt[s], goff, N_NODES, N_NODES, cnt_g);
            k_scan_b<<<1, 512, 0, stream>>>(blksum, nscan);
            k_scan_c<<<nscan, 512, 0, stream>>>(row_ptr, blksum, N_NODES, E_EDGES);
            k_fill<<<512, 256, 0, stream>>>(esrc, esrc, edst, edst, E_EDGES, 0,
                                            row_ptr, fill_cnt, dinv, edges);

            k_gemm128<<<gblk, 256, 0, stream>>>(x[s], x[s], W1, hA, N_NODES, N_NODES);
            k_agg<0><<<ablk, 256, 0, stream>>>(hA, hA, dinv, row_ptr, edges, b1,
                                               hB, hB, bt[s], bt[s], goff, N_NODES, N_NODES, nullptr);
            k_gemm128<<<gblk, 256, 0, stream>>>(hB, hB, W2, hA, N_NODES, N_NODES);
            k_agg<0><<<ablk, 256, 0, stream>>>(hA, hA, dinv, row_ptr, edges, b2,
                                               hB, hB, bt[s], bt[s], goff, N_NODES, N_NODES, nullptr);
            k_agg<2><<<ablk, 256, 0, stream>>>(hB, hB, dinv, row_ptr, edges, nullptr,
                                               nullptr, nullptr, bt[s], bt[s], goff,
                                               N_NODES, N_NODES, pool_s);
        }
    }

    k_divpool<<<(2 * NGRAPH * HDIM + 255) / 256, 256, 0, stream>>>(pool_s, cnt_g);

    // layer-3 weight applied to pooled means (linearity): zcat[g, s*128+:] =
    // pool_side_s[g] @ W3 + b3
    for (int s = 0; s < 2; ++s)
        k_gemm<<<dim3(NGRAPH / 64, HDIM / 64), 256, 0, stream>>>(
            pool_s + (size_t)s * NGRAPH * HDIM, W3, b3, zcat + s * HDIM,
            NGRAPH, HDIM, HDIM, 2 * HDIM, 0);

    // MLP head
    k_gemm<<<dim3(NGRAPH / 64, (4 * HDIM) / 64), 256, 0, stream>>>(zcat, Wc1, bc1, z1, NGRAPH, 4 * HDIM, 2 * HDIM, 4 * HDIM, 1);
    k_gemm<<<dim3(NGRAPH / 64, (2 * HDIM) / 64), 256, 0, stream>>>(z1, Wc2, bc2, z2, NGRAPH, 2 * HDIM, 4 * HDIM, 2 * HDIM, 1);
    k_gemm<<<dim3(NGRAPH / 64, 1), 256, 0, stream>>>(z2, Wc3, bc3, out, NGRAPH, OUTC, 2 * HDIM, OUTC, 0);
}

// Round 5
// 704.720 us; speedup vs baseline: 1.3883x; 1.0905x over previous
//
#include <hip/hip_runtime.h>
#include <math.h>

#define N_NODES 50000
#define E_EDGES 500000
#define HDIM    128
#define OUTC    2
#define NGRAPH  512

typedef _Float16 f16x8 __attribute__((ext_vector_type(8)));
typedef float    f32x4 __attribute__((ext_vector_type(4)));

// ---------------- utility: zero a span of 4-byte words ----------------
__global__ void k_zero(int* __restrict__ p, int n) {
    int i = blockIdx.x * blockDim.x + threadIdx.x;
    int stride = gridDim.x * blockDim.x;
    for (; i < n; i += stride) p[i] = 0;
}

// ---------------- edge histogram over dst (1 or 2 sides) -------------------
__global__ void k_hist(const int* __restrict__ d0, const int* __restrict__ d1,
                       int ecnt, int off1, int* __restrict__ cnt) {
    int i = blockIdx.x * blockDim.x + threadIdx.x;
    int stride = gridDim.x * blockDim.x;
    for (; i < ecnt; i += stride) {
        int d = (i < E_EDGES) ? d0[i] : d1[i - E_EDGES] + off1;
        atomicAdd(&cnt[d], 1);
    }
}

// ---------------- scan stage A -------------------------------------------
__global__ void k_scan_a(const int* __restrict__ cnt, int* __restrict__ excl,
                         int* __restrict__ blksum, float* __restrict__ dinv,
                         const int* __restrict__ bt0, const int* __restrict__ bt1,
                         int goff0, int nn, int nside, float* __restrict__ cnt_g) {
    __shared__ int s[512];
    int t = threadIdx.x;
    int i = blockIdx.x * 512 + t;
    int v = 0;
    if (i < nn) {
        v = cnt[i];
        dinv[i] = 1.0f / sqrtf((float)(v + 1));
        int g = (i < nside) ? bt0[i] + goff0 : bt1[i - nside] + NGRAPH;
        atomicAdd(&cnt_g[g], 1.0f);
    }
    s[t] = v; __syncthreads();
    for (int off = 1; off < 512; off <<= 1) {
        int add = (t >= off) ? s[t - off] : 0;
        __syncthreads();
        s[t] += add;
        __syncthreads();
    }
    if (i < nn) excl[i] = s[t] - v;
    if (t == 511) blksum[blockIdx.x] = s[511];
}

// ---------------- scan stage B ---------------------------------------------
__global__ void k_scan_b(int* __restrict__ blksum, int nb) {
    __shared__ int s[512];
    int t = threadIdx.x;
    int v = (t < nb) ? blksum[t] : 0;
    s[t] = v; __syncthreads();
    for (int off = 1; off < 512; off <<= 1) {
        int add = (t >= off) ? s[t - off] : 0;
        __syncthreads();
        s[t] += add;
        __syncthreads();
    }
    if (t < nb) blksum[t] = s[t] - v;
}

// ---------------- scan stage C ---------------------------------------------
__global__ void k_scan_c(int* __restrict__ excl, const int* __restrict__ blksum,
                         int nn, int tot) {
    int t = threadIdx.x;
    int i = blockIdx.x * 512 + t;
    if (i < nn) excl[i] += blksum[blockIdx.x];
    if (i == 0) excl[nn] = tot;
}

// ---------------- CSR fill: (global src, weight) grouped by dst ------------
__global__ void k_fill(const int* __restrict__ s0, const int* __restrict__ s1,
                       const int* __restrict__ d0, const int* __restrict__ d1,
                       int ecnt, int off1,
                       const int* __restrict__ row_ptr, int* __restrict__ fill_cnt,
                       const float* __restrict__ dinv, int2* __restrict__ edges) {
    int i = blockIdx.x * blockDim.x + threadIdx.x;
    int stride = gridDim.x * blockDim.x;
    for (; i < ecnt; i += stride) {
        int d, sg;
        if (i < E_EDGES) { sg = s0[i]; d = d0[i]; }
        else             { sg = s1[i - E_EDGES] + off1; d = d1[i - E_EDGES] + off1; }
        int p = atomicAdd(&fill_cnt[d], 1);
        float w = dinv[sg] * dinv[d];
        edges[row_ptr[d] + p] = make_int2(sg, __float_as_int(w));
    }
}

// ---------------- fp32 -> split-f16 conversion (x inputs) ------------------
// element i (pair granularity): v = hi + lo with hi = f16(v), lo = f16(v-hi).
__global__ void k_cvt(const float* __restrict__ x0, const float* __restrict__ x1,
                      int nside_pairs, int total_pairs,
                      _Float16* __restrict__ hi, _Float16* __restrict__ lo) {
    int i = blockIdx.x * blockDim.x + threadIdx.x;
    int stride = gridDim.x * blockDim.x;
    for (; i < total_pairs; i += stride) {
        float2 v = (i < nside_pairs) ? ((const float2*)x0)[i]
                                     : ((const float2*)x1)[i - nside_pairs];
        _Float16 hx = (_Float16)v.x, hy = (_Float16)v.y;
        _Float16 lx = (_Float16)(v.x - (float)hx), ly = (_Float16)(v.y - (float)hy);
        union { _Float16 h[2]; unsigned u; } ph, pl;
        ph.h[0] = hx; ph.h[1] = hy;
        pl.h[0] = lx; pl.h[1] = ly;
        ((unsigned*)hi)[i] = ph.u;
        ((unsigned*)lo)[i] = pl.u;
    }
}

// ---------------- weight prep: W (K x N fp32) -> W^T split planes ----------
// Wthi[n*128+k] = f16(W[k*128+n]); Wtlo = residual.  16384 elements.
__global__ void k_cvtw(const float* __restrict__ W,
                       _Float16* __restrict__ thi, _Float16* __restrict__ tlo) {
    int i = blockIdx.x * blockDim.x + threadIdx.x;
    if (i >= 128 * 128) return;
    int n = i >> 7, k = i & 127;
    float v = W[k * 128 + n];
    _Float16 h = (_Float16)v;
    thi[i] = h;
    tlo[i] = (_Float16)(v - (float)h);
}

// ---------------- MFMA split-f16 GEMM: C(f32, Mx128) = A @ W ---------------
// A given as two f16 planes (hi, lo), M x 128 row-major. W given as W^T split
// planes (128n x 128k). D = Ahi*Bhi + Ahi*Blo + Alo*Bhi (lo*lo dropped,
// ~2^-22 relative). Block: 256 thr = 2x2 waves, tile 128x128, KC=32/chunk.
// Frag layouts per m89/m91/m120: A[m=lane&15][k=quad*8+j]; D row=quad*4+reg,
// col=lane&15.
__global__ __launch_bounds__(256) void k_gemm_splitf16(
        const _Float16* __restrict__ Ahi, const _Float16* __restrict__ Alo,
        const _Float16* __restrict__ Bhi, const _Float16* __restrict__ Blo,
        float* __restrict__ C, int M) {
    __shared__ _Float16 sA[2][128][40];   // [plane][m][k + pad8] (16B-aligned rows)
    __shared__ _Float16 sB[2][128][40];   // [plane][n][k + pad8]
    int tid = threadIdx.x;
    int wave = tid >> 6, lane = tid & 63;
    int wm = (wave >> 1) * 64;
    int wn = (wave & 1) * 64;
    int quad = lane >> 4, fm = lane & 15;
    int row0 = blockIdx.x * 128;

    int lr = tid >> 2;              // 0..63 staging row
    int lk = (tid & 3) * 8;         // 0,8,16,24

    f32x4 acc[4][4] = {};

    const float4 z4 = make_float4(0.f, 0.f, 0.f, 0.f);
    for (int kc = 0; kc < 128; kc += 32) {
        int r1 = row0 + lr, r2 = row0 + lr + 64;
        bool ok1 = r1 < M, ok2 = r2 < M;
        float4 ah1 = ok1 ? *(const float4*)(Ahi + (size_t)r1 * 128 + kc + lk) : z4;
        float4 al1 = ok1 ? *(const float4*)(Alo + (size_t)r1 * 128 + kc + lk) : z4;
        float4 ah2 = ok2 ? *(const float4*)(Ahi + (size_t)r2 * 128 + kc + lk) : z4;
        float4 al2 = ok2 ? *(const float4*)(Alo + (size_t)r2 * 128 + kc + lk) : z4;
        float4 bh1 = *(const float4*)(Bhi + (size_t)lr * 128 + kc + lk);
        float4 bl1 = *(const float4*)(Blo + (size_t)lr * 128 + kc + lk);
        float4 bh2 = *(const float4*)(Bhi + (size_t)(lr + 64) * 128 + kc + lk);
        float4 bl2 = *(const float4*)(Blo + (size_t)(lr + 64) * 128 + kc + lk);
        __syncthreads();            // prior chunk's readers done
        *(float4*)&sA[0][lr][lk]      = ah1;
        *(float4*)&sA[1][lr][lk]      = al1;
        *(float4*)&sA[0][lr + 64][lk] = ah2;
        *(float4*)&sA[1][lr + 64][lk] = al2;
        *(float4*)&sB[0][lr][lk]      = bh1;
        *(float4*)&sB[1][lr][lk]      = bl1;
        *(float4*)&sB[0][lr + 64][lk] = bh2;
        *(float4*)&sB[1][lr + 64][lk] = bl2;
        __syncthreads();

        f16x8 afh[4], afl[4], bfh[4], bfl[4];
#pragma unroll
        for (int mi = 0; mi < 4; mi++) {
            afh[mi] = *(const f16x8*)&sA[0][wm + mi * 16 + fm][quad * 8];
            afl[mi] = *(const f16x8*)&sA[1][wm + mi * 16 + fm][quad * 8];
        }
#pragma unroll
        for (int ni = 0; ni < 4; ni++) {
            bfh[ni] = *(const f16x8*)&sB[0][wn + ni * 16 + fm][quad * 8];
            bfl[ni] = *(const f16x8*)&sB[1][wn + ni * 16 + fm][quad * 8];
        }
#pragma unroll
        for (int mi = 0; mi < 4; mi++)
#pragma unroll
            for (int ni = 0; ni < 4; ni++) {
                acc[mi][ni] = __builtin_amdgcn_mfma_f32_16x16x32_f16(afh[mi], bfh[ni], acc[mi][ni], 0, 0, 0);
                acc[mi][ni] = __builtin_amdgcn_mfma_f32_16x16x32_f16(afh[mi], bfl[ni], acc[mi][ni], 0, 0, 0);
                acc[mi][ni] = __builtin_amdgcn_mfma_f32_16x16x32_f16(afl[mi], bfh[ni], acc[mi][ni], 0, 0, 0);
            }
    }

#pragma unroll
    for (int mi = 0; mi < 4; mi++)
#pragma unroll
        for (int reg = 0; reg < 4; reg++) {
            int r = row0 + wm + mi * 16 + quad * 4 + reg;
            if (r >= M) continue;
#pragma unroll
            for (int ni = 0; ni < 4; ni++)
                C[(size_t)r * 128 + wn + ni * 16 + fm] = acc[mi][ni][reg];
        }
}

// ---------------- generic fp32 GEMM (small pool/head GEMMs) ----------------
__global__ __launch_bounds__(256) void k_gemm(
        const float* __restrict__ A, const float* __restrict__ B,
        const float* __restrict__ bias, float* __restrict__ C,
        int M, int Nn, int K, int ldc, int act) {
    __shared__ float As[16][64];
    __shared__ float Bs[16][68];
    int tid = threadIdx.x;
    int tx = tid & 15, ty = tid >> 4;
    int row0 = blockIdx.x * 64, col0 = blockIdx.y * 64;
    float acc[4][4] = {};
    int arow = tid >> 2;
    int acol = (tid & 3) * 4;
    int brow = tid >> 4;
    int bcol = (tid & 15) * 4;

    for (int k0 = 0; k0 < K; k0 += 16) {
        float4 av = make_float4(0.f, 0.f, 0.f, 0.f);
        int ar = row0 + arow;
        if (ar < M) av = *(const float4*)(A + (size_t)ar * K + k0 + acol);
        As[acol + 0][arow] = av.x;
        As[acol + 1][arow] = av.y;
        As[acol + 2][arow] = av.z;
        As[acol + 3][arow] = av.w;

        float4 bv = make_float4(0.f, 0.f, 0.f, 0.f);
        const float* Brow = B + (size_t)(k0 + brow) * Nn;
        int bc = col0 + bcol;
        if (bc + 3 < Nn) {
            bv = *(const float4*)(Brow + bc);
        } else {
            if (bc     < Nn) bv.x = Brow[bc];
            if (bc + 1 < Nn) bv.y = Brow[bc + 1];
            if (bc + 2 < Nn) bv.z = Brow[bc + 2];
        }
        Bs[brow][bcol + 0] = bv.x;
        Bs[brow][bcol + 1] = bv.y;
        Bs[brow][bcol + 2] = bv.z;
        Bs[brow][bcol + 3] = bv.w;
        __syncthreads();

#pragma unroll
        for (int k = 0; k < 16; k++) {
            float4 a = *(const float4*)&As[k][ty * 4];
            float4 b = *(const float4*)&Bs[k][tx * 4];
            acc[0][0] += a.x * b.x; acc[0][1] += a.x * b.y; acc[0][2] += a.x * b.z; acc[0][3] += a.x * b.w;
            acc[1][0] += a.y * b.x; acc[1][1] += a.y * b.y; acc[1][2] += a.y * b.z; acc[1][3] += a.y * b.w;
            acc[2][0] += a.z * b.x; acc[2][1] += a.z * b.y; acc[2][2] += a.z * b.z; acc[2][3] += a.z * b.w;
            acc[3][0] += a.w * b.x; acc[3][1] += a.w * b.y; acc[3][2] += a.w * b.z; acc[3][3] += a.w * b.w;
        }
        __syncthreads();
    }

#pragma unroll
    for (int i = 0; i < 4; i++) {
        int r = row0 + ty * 4 + i;
        if (r >= M) continue;
#pragma unroll
        for (int j = 0; j < 4; j++) {
            int c = col0 + tx * 4 + j;
            if (c >= Nn) continue;
            float v = acc[i][j];
            if (bias) v += bias[c];
            if (act) v = fmaxf(v, 0.0f);
            C[(size_t)r * ldc + c] = v;
        }
    }
}

// ---------------- CSR aggregation: scalar metadata, 8 gathers in flight ----
// MODE 0: out = relu(agg + bias), written split-f16 (PACK=1) or fp32 (PACK=0)
// MODE 2: pool[gid] += agg (atomic)
template <int MODE, int PACK>
__global__ __launch_bounds__(256) void k_agg(
        const float* __restrict__ H, const float* __restrict__ dinv,
        const int* __restrict__ row_ptr, const int2* __restrict__ edges,
        const float* __restrict__ bias,
        _Float16* __restrict__ outHi, _Float16* __restrict__ outLo,
        float* __restrict__ outF,
        const int* __restrict__ bt0, const int* __restrict__ bt1,
        int goff0, int nnodes, int nside, float* __restrict__ pool) {
    int wave = threadIdx.x >> 6, lane = threadIdx.x & 63;
    int node = blockIdx.x * 4 + wave;
    if (node >= nnodes) return;

    float di = dinv[node];
    float2 hv = ((const float2*)(H + (size_t)node * HDIM))[lane];
    float wself = di * di;
    float ax = hv.x * wself;
    float ay = hv.y * wself;

    int rs = __builtin_amdgcn_readfirstlane(row_ptr[node]);
    int re = __builtin_amdgcn_readfirstlane(row_ptr[node + 1]);
    for (int base = rs; base < re; base += 8) {
        int nrem = re - base;
        int m = nrem - 1;
        int i1 = 1 < nrem ? 1 : m;
        int i2 = 2 < nrem ? 2 : m;
        int i3 = 3 < nrem ? 3 : m;
        int i4 = 4 < nrem ? 4 : m;
        int i5 = 5 < nrem ? 5 : m;
        int i6 = 6 < nrem ? 6 : m;
        int i7 = 7 < nrem ? 7 : m;
        int2 E0 = edges[base];
        int2 E1 = edges[base + i1];
        int2 E2 = edges[base + i2];
        int2 E3 = edges[base + i3];
        int2 E4 = edges[base + i4];
        int2 E5 = edges[base + i5];
        int2 E6 = edges[base + i6];
        int2 E7 = edges[base + i7];
        float2 v0 = ((const float2*)(H + (size_t)E0.x * HDIM))[lane];
        float2 v1 = ((const float2*)(H + (size_t)E1.x * HDIM))[lane];
        float2 v2 = ((const float2*)(H + (size_t)E2.x * HDIM))[lane];
        float2 v3 = ((const float2*)(H + (size_t)E3.x * HDIM))[lane];
        float2 v4 = ((const float2*)(H + (size_t)E4.x * HDIM))[lane];
        float2 v5 = ((const float2*)(H + (size_t)E5.x * HDIM))[lane];
        float2 v6 = ((const float2*)(H + (size_t)E6.x * HDIM))[lane];
        float2 v7 = ((const float2*)(H + (size_t)E7.x * HDIM))[lane];
        float w0 = __int_as_float(E0.y);
        float w1 = 1 < nrem ? __int_as_float(E1.y) : 0.f;
        float w2 = 2 < nrem ? __int_as_float(E2.y) : 0.f;
        float w3 = 3 < nrem ? __int_as_float(E3.y) : 0.f;
        float w4 = 4 < nrem ? __int_as_float(E4.y) : 0.f;
        float w5 = 5 < nrem ? __int_as_float(E5.y) : 0.f;
        float w6 = 6 < nrem ? __int_as_float(E6.y) : 0.f;
        float w7 = 7 < nrem ? __int_as_float(E7.y) : 0.f;
        ax = fmaf(v0.x, w0, ax); ay = fmaf(v0.y, w0, ay);
        ax = fmaf(v1.x, w1, ax); ay = fmaf(v1.y, w1, ay);
        ax = fmaf(v2.x, w2, ax); ay = fmaf(v2.y, w2, ay);
        ax = fmaf(v3.x, w3, ax); ay = fmaf(v3.y, w3, ay);
        ax = fmaf(v4.x, w4, ax); ay = fmaf(v4.y, w4, ay);
        ax = fmaf(v5.x, w5, ax); ay = fmaf(v5.y, w5, ay);
        ax = fmaf(v6.x, w6, ax); ay = fmaf(v6.y, w6, ay);
        ax = fmaf(v7.x, w7, ax); ay = fmaf(v7.y, w7, ay);
    }

    if (MODE == 2) {
        int g = (node < nside) ? bt0[node] + goff0 : bt1[node - nside] + NGRAPH;
        float* p = pool + (size_t)g * HDIM + lane * 2;
        atomicAdd(p,     ax);
        atomicAdd(p + 1, ay);
    } else {
        float ox = fmaxf(ax + bias[lane * 2],     0.0f);
        float oy = fmaxf(ay + bias[lane * 2 + 1], 0.0f);
        if (PACK) {
            _Float16 hx = (_Float16)ox, hy = (_Float16)oy;
            _Float16 lx = (_Float16)(ox - (float)hx), ly = (_Float16)(oy - (float)hy);
            union { _Float16 h[2]; unsigned u; } ph, pl;
            ph.h[0] = hx; ph.h[1] = hy;
            pl.h[0] = lx; pl.h[1] = ly;
            ((unsigned*)(outHi + (size_t)node * HDIM))[lane] = ph.u;
            ((unsigned*)(outLo + (size_t)node * HDIM))[lane] = pl.u;
        } else {
            ((float2*)(outF + (size_t)node * HDIM))[lane] = make_float2(ox, oy);
        }
    }
}

// ---------------- divide pooled sums by graph node counts ------------------
__global__ void k_divpool(float* __restrict__ pool, const float* __restrict__ cnt_g) {
    int i = blockIdx.x * blockDim.x + threadIdx.x;
    if (i < 2 * NGRAPH * HDIM) pool[i] /= fmaxf(cnt_g[i >> 7], 1.0f);
}

extern "C" void kernel_launch(void* const* d_in, const int* in_sizes, int n_in,
                              void* d_out, int out_size, void* d_ws, size_t ws_size,
                              hipStream_t stream) {
    (void)in_sizes; (void)n_in; (void)out_size;

    const float* x[2]  = {(const float*)d_in[0], (const float*)d_in[1]};
    const int*   ei[2] = {(const int*)d_in[2], (const int*)d_in[3]};
    const int*   bt[2] = {(const int*)d_in[4], (const int*)d_in[5]};
    const float* W1  = (const float*)d_in[6];  const float* b1  = (const float*)d_in[7];
    const float* W2  = (const float*)d_in[8];  const float* b2  = (const float*)d_in[9];
    const float* W3  = (const float*)d_in[10]; const float* b3  = (const float*)d_in[11];
    const float* Wc1 = (const float*)d_in[12]; const float* bc1 = (const float*)d_in[13];
    const float* Wc2 = (const float*)d_in[14]; const float* bc2 = (const float*)d_in[15];
    const float* Wc3 = (const float*)d_in[16]; const float* bc3 = (const float*)d_in[17];
    float* out = (float*)d_out;

    const bool batched = ws_size >= 120ull * 1000 * 1000;
    const int NN = batched ? 2 * N_NODES : N_NODES;
    const int NE = batched ? 2 * E_EDGES : E_EDGES;

    char* ws = (char*)d_ws;
    size_t off = 0;
    auto carve = [&](size_t bytes) -> char* {
        char* p = ws + off;
        off += (bytes + 255) & ~(size_t)255;
        return p;
    };

    int*   edge_cnt = (int*)  carve((size_t)NN * 4);
    int*   fill_cnt = (int*)  carve((size_t)NN * 4);
    float* pool_s   = (float*)carve((size_t)2 * NGRAPH * HDIM * 4);
    float* cnt_g    = (float*)carve((size_t)2 * NGRAPH * 4);
    float* dinv     = (float*)carve((size_t)NN * 4);
    int*   row_ptr  = (int*)  carve((size_t)(NN + 1) * 4);
    int2*  edges    = (int2*) carve((size_t)NE * 8);
    int*   blksum   = (int*)  carve(1024 * 4);
    _Float16* wt    = (_Float16*)carve(4 * 128 * 128 * 2);   // W1t hi/lo, W2t hi/lo
    _Float16* hS    = (_Float16*)carve((size_t)NN * HDIM * 4); // split planes OR fp32 alias
    float* hA       = (float*)carve((size_t)NN * HDIM * 4);
    float* zcat     = (float*)carve((size_t)NGRAPH * 2 * HDIM * 4);
    float* z1       = (float*)carve((size_t)NGRAPH * 4 * HDIM * 4);
    float* z2       = (float*)carve((size_t)NGRAPH * 2 * HDIM * 4);

    _Float16* w1hi = wt;
    _Float16* w1lo = wt + 128 * 128;
    _Float16* w2hi = wt + 2 * 128 * 128;
    _Float16* w2lo = wt + 3 * 128 * 128;
    _Float16* hShi = hS;
    _Float16* hSlo = hS + (size_t)NN * HDIM;
    float*    hSf  = (float*)hS;

    int zeroA_words = (int)(((char*)pool_s - (char*)edge_cnt) / 4);
    int zeroB_words = (int)(((char*)dinv   - (char*)pool_s)   / 4);

    k_zero<<<256, 256, 0, stream>>>((int*)pool_s, zeroB_words);
    k_cvtw<<<64, 256, 0, stream>>>(W1, w1hi, w1lo);
    k_cvtw<<<64, 256, 0, stream>>>(W2, w2hi, w2lo);

    const int gblk = (NN + 127) / 128;

    if (batched) {
        const int nscan = (2 * N_NODES + 511) / 512;
        const int ablk  = (2 * N_NODES + 3) / 4;

        k_zero<<<512, 256, 0, stream>>>(edge_cnt, zeroA_words);
        k_hist<<<1024, 256, 0, stream>>>(ei[0] + E_EDGES, ei[1] + E_EDGES,
                                         2 * E_EDGES, N_NODES, edge_cnt);
        k_scan_a<<<nscan, 512, 0, stream>>>(edge_cnt, row_ptr, blksum, dinv,
                                            bt[0], bt[1], 0, 2 * N_NODES, N_NODES, cnt_g);
        k_scan_b<<<1, 512, 0, stream>>>(blksum, nscan);
        k_scan_c<<<nscan, 512, 0, stream>>>(row_ptr, blksum, 2 * N_NODES, 2 * E_EDGES);
        k_fill<<<1024, 256, 0, stream>>>(ei[0], ei[1], ei[0] + E_EDGES, ei[1] + E_EDGES,
                                         2 * E_EDGES, N_NODES, row_ptr, fill_cnt, dinv, edges);

        k_cvt<<<1024, 256, 0, stream>>>(x[0], x[1], N_NODES * HDIM / 2,
                                        2 * N_NODES * HDIM / 2, hShi, hSlo);

        k_gemm_splitf16<<<gblk, 256, 0, stream>>>(hShi, hSlo, w1hi, w1lo, hA, 2 * N_NODES);
        k_agg<0, 1><<<ablk, 256, 0, stream>>>(hA, dinv, row_ptr, edges, b1,
                                              hShi, hSlo, nullptr, bt[0], bt[1], 0,
                                              2 * N_NODES, N_NODES, nullptr);
        k_gemm_splitf16<<<gblk, 256, 0, stream>>>(hShi, hSlo, w2hi, w2lo, hA, 2 * N_NODES);
        k_agg<0, 0><<<ablk, 256, 0, stream>>>(hA, dinv, row_ptr, edges, b2,
                                              nullptr, nullptr, hSf, bt[0], bt[1], 0,
                                              2 * N_NODES, N_NODES, nullptr);
        k_agg<2, 0><<<ablk, 256, 0, stream>>>(hSf, dinv, row_ptr, edges, nullptr,
                                              nullptr, nullptr, nullptr, bt[0], bt[1], 0,
                                              2 * N_NODES, N_NODES, pool_s);
    } else {
        const int nscan = (N_NODES + 511) / 512;
        const int ablk  = (N_NODES + 3) / 4;

        for (int s = 0; s < 2; ++s) {
            const int* esrc = ei[s];
            const int* edst = ei[s] + E_EDGES;
            int goff = s * NGRAPH;

            k_zero<<<512, 256, 0, stream>>>(edge_cnt, zeroA_words);
            k_hist<<<512, 256, 0, stream>>>(edst, edst, E_EDGES, 0, edge_cnt);
            k_scan_a<<<nscan, 512, 0, stream>>>(edge_cnt, row_ptr, blksum, dinv,
                                                bt[s], bt[s], goff, N_NODES, N_NODES, cnt_g);
            k_scan_b<<<1, 512, 0, stream>>>(blksum, nscan);
            k_scan_c<<<nscan, 512, 0, stream>>>(row_ptr, blksum, N_NODES, E_EDGES);
            k_fill<<<512, 256, 0, stream>>>(esrc, esrc, edst, edst, E_EDGES, 0,
                                            row_ptr, fill_cnt, dinv, edges);

            k_cvt<<<1024, 256, 0, stream>>>(x[s], x[s], N_NODES * HDIM / 2,
                                            N_NODES * HDIM / 2, hShi, hSlo);

            k_gemm_splitf16<<<gblk, 256, 0, stream>>>(hShi, hSlo, w1hi, w1lo, hA, N_NODES);
            k_agg<0, 1><<<ablk, 256, 0, stream>>>(hA, dinv, row_ptr, edges, b1,
                                                  hShi, hSlo, nullptr, bt[s], bt[s], goff,
                                                  N_NODES, N_NODES, nullptr);
            k_gemm_splitf16<<<gblk, 256, 0, stream>>>(hShi, hSlo, w2hi, w2lo, hA, N_NODES);
            k_agg<0, 0><<<ablk, 256, 0, stream>>>(hA, dinv, row_ptr, edges, b2,
                                                  nullptr, nullptr, hSf, bt[s], bt[s], goff,
                                                  N_NODES, N_NODES, nullptr);
            k_agg<2, 0><<<ablk, 256, 0, stream>>>(hSf, dinv, row_ptr, edges, nullptr,
                                                  nullptr, nullptr, nullptr, bt[s], bt[s], goff,
                                                  N_NODES, N_NODES, pool_s);
        }
    }

    k_divpool<<<(2 * NGRAPH * HDIM + 255) / 256, 256, 0, stream>>>(pool_s, cnt_g);

    for (int s = 0; s < 2; ++s)
        k_gemm<<<dim3(NGRAPH / 64, HDIM / 64), 256, 0, stream>>>(
            pool_s + (size_t)s * NGRAPH * HDIM, W3, b3, zcat + s * HDIM,
            NGRAPH, HDIM, HDIM, 2 * HDIM, 0);

    k_gemm<<<dim3(NGRAPH / 64, (4 * HDIM) / 64), 256, 0, stream>>>(zcat, Wc1, bc1, z1, NGRAPH, 4 * HDIM, 2 * HDIM, 4 * HDIM, 1);
    k_gemm<<<dim3(NGRAPH / 64, (2 * HDIM) / 64), 256, 0, stream>>>(z1, Wc2, bc2, z2, NGRAPH, 2 * HDIM, 4 * HDIM, 2 * HDIM, 1);
    k_gemm<<<dim3(NGRAPH / 64, 1), 256, 0, stream>>>(z2, Wc3, bc3, out, NGRAPH, OUTC, 2 * HDIM, OUTC, 0);
}

// Round 6
// 676.618 us; speedup vs baseline: 1.4460x; 1.0415x over previous
//
#include <hip/hip_runtime.h>
#include <math.h>

#define N_NODES 50000
#define E_EDGES 500000
#define HDIM    128
#define OUTC    2
#define NGRAPH  512

typedef _Float16 f16x8 __attribute__((ext_vector_type(8)));
typedef float    f32x4 __attribute__((ext_vector_type(4)));

// ---------------- fused prep: zero counters/pool + weight split-transpose --
__global__ void k_prep(int* __restrict__ zA, int nA, int* __restrict__ zB, int nB,
                       const float* __restrict__ W1, const float* __restrict__ W2,
                       _Float16* __restrict__ w1hi, _Float16* __restrict__ w1lo,
                       _Float16* __restrict__ w2hi, _Float16* __restrict__ w2lo) {
    int i = blockIdx.x * blockDim.x + threadIdx.x;
    int stride = gridDim.x * blockDim.x;
    for (int j = i; j < nA; j += stride) zA[j] = 0;
    for (int j = i; j < nB; j += stride) zB[j] = 0;
    for (int j = i; j < 128 * 128; j += stride) {
        int n = j >> 7, k = j & 127;
        float v = W1[k * 128 + n];
        _Float16 h = (_Float16)v;
        w1hi[j] = h; w1lo[j] = (_Float16)(v - (float)h);
        v = W2[k * 128 + n];
        h = (_Float16)v;
        w2hi[j] = h; w2lo[j] = (_Float16)(v - (float)h);
    }
}

// ---------------- edge histogram over dst (1 or 2 sides) -------------------
__global__ void k_hist(const int* __restrict__ d0, const int* __restrict__ d1,
                       int ecnt, int off1, int* __restrict__ cnt) {
    int i = blockIdx.x * blockDim.x + threadIdx.x;
    int stride = gridDim.x * blockDim.x;
    for (; i < ecnt; i += stride) {
        int d = (i < E_EDGES) ? d0[i] : d1[i - E_EDGES] + off1;
        atomicAdd(&cnt[d], 1);
    }
}

// ---------------- scan stage A ---------------------------------------------
__global__ void k_scan_a(const int* __restrict__ cnt, int* __restrict__ excl,
                         int* __restrict__ blksum, float* __restrict__ dinv,
                         const int* __restrict__ bt0, const int* __restrict__ bt1,
                         int goff0, int nn, int nside, float* __restrict__ cnt_g) {
    __shared__ int s[512];
    int t = threadIdx.x;
    int i = blockIdx.x * 512 + t;
    int v = 0;
    if (i < nn) {
        v = cnt[i];
        dinv[i] = 1.0f / sqrtf((float)(v + 1));
        int g = (i < nside) ? bt0[i] + goff0 : bt1[i - nside] + NGRAPH;
        atomicAdd(&cnt_g[g], 1.0f);
    }
    s[t] = v; __syncthreads();
    for (int off = 1; off < 512; off <<= 1) {
        int add = (t >= off) ? s[t - off] : 0;
        __syncthreads();
        s[t] += add;
        __syncthreads();
    }
    if (i < nn) excl[i] = s[t] - v;
    if (t == 511) blksum[blockIdx.x] = s[511];
}

// ---------------- scan stage B ---------------------------------------------
__global__ void k_scan_b(int* __restrict__ blksum, int nb) {
    __shared__ int s[512];
    int t = threadIdx.x;
    int v = (t < nb) ? blksum[t] : 0;
    s[t] = v; __syncthreads();
    for (int off = 1; off < 512; off <<= 1) {
        int add = (t >= off) ? s[t - off] : 0;
        __syncthreads();
        s[t] += add;
        __syncthreads();
    }
    if (t < nb) blksum[t] = s[t] - v;
}

// ---------------- scan stage C ---------------------------------------------
__global__ void k_scan_c(int* __restrict__ excl, const int* __restrict__ blksum,
                         int nn, int tot) {
    int t = threadIdx.x;
    int i = blockIdx.x * 512 + t;
    if (i < nn) excl[i] += blksum[blockIdx.x];
    if (i == 0) excl[nn] = tot;
}

// ---------------- CSR fill: (global src, weight) grouped by dst ------------
__global__ void k_fill(const int* __restrict__ s0, const int* __restrict__ s1,
                       const int* __restrict__ d0, const int* __restrict__ d1,
                       int ecnt, int off1,
                       const int* __restrict__ row_ptr, int* __restrict__ fill_cnt,
                       const float* __restrict__ dinv, int2* __restrict__ edges) {
    int i = blockIdx.x * blockDim.x + threadIdx.x;
    int stride = gridDim.x * blockDim.x;
    for (; i < ecnt; i += stride) {
        int d, sg;
        if (i < E_EDGES) { sg = s0[i]; d = d0[i]; }
        else             { sg = s1[i - E_EDGES] + off1; d = d1[i - E_EDGES] + off1; }
        int p = atomicAdd(&fill_cnt[d], 1);
        float w = dinv[sg] * dinv[d];
        edges[row_ptr[d] + p] = make_int2(sg, __float_as_int(w));
    }
}

__device__ inline void cvt8(const float4& p, const float4& q, f16x8& h, f16x8& l) {
    float v[8] = {p.x, p.y, p.z, p.w, q.x, q.y, q.z, q.w};
#pragma unroll
    for (int i = 0; i < 8; i++) {
        _Float16 hh = (_Float16)v[i];
        h[i] = hh;
        l[i] = (_Float16)(v[i] - (float)hh);
    }
}

// ---------------- MFMA split-f16 GEMM: C(f32, Mx128) = A @ W ---------------
// ASRC=0: A from split-f16 planes (Ahi/Alo, single base).
// ASRC=1: A fp32, dual base (A0f rows [0,nside), A1f rows [nside,M)),
//         converted to hi/lo in-register during staging.
// W as W^T split planes (128n x 128k). D = Ah*Bh + Ah*Bl + Al*Bh.
template <int ASRC>
__global__ __launch_bounds__(256) void k_gemm_split(
        const float* __restrict__ A0f, const float* __restrict__ A1f, int nside,
        const _Float16* __restrict__ Ahi, const _Float16* __restrict__ Alo,
        const _Float16* __restrict__ Bhi, const _Float16* __restrict__ Blo,
        float* __restrict__ C, int M) {
    __shared__ _Float16 sA[2][128][40];   // [plane][m][k+pad8] (80B row stride)
    __shared__ _Float16 sB[2][128][40];
    int tid = threadIdx.x;
    int wave = tid >> 6, lane = tid & 63;
    int wm = (wave >> 1) * 64;
    int wn = (wave & 1) * 64;
    int quad = lane >> 4, fm = lane & 15;
    int row0 = blockIdx.x * 128;

    int lr = tid >> 2;              // 0..63 staging row
    int lk = (tid & 3) * 8;         // 0,8,16,24

    f32x4 acc[4][4] = {};
    const float4 z4 = make_float4(0.f, 0.f, 0.f, 0.f);

    for (int kc = 0; kc < 128; kc += 32) {
        int r1 = row0 + lr, r2 = row0 + lr + 64;
        bool ok1 = r1 < M, ok2 = r2 < M;
        f16x8 ah1, al1, ah2, al2;
        if (ASRC == 1) {
            const float* p1 = (r1 < nside) ? A0f + (size_t)r1 * 128
                                           : A1f + (size_t)(r1 - nside) * 128;
            const float* p2 = (r2 < nside) ? A0f + (size_t)r2 * 128
                                           : A1f + (size_t)(r2 - nside) * 128;
            float4 a = ok1 ? *(const float4*)(p1 + kc + lk) : z4;
            float4 b = ok1 ? *(const float4*)(p1 + kc + lk + 4) : z4;
            float4 c = ok2 ? *(const float4*)(p2 + kc + lk) : z4;
            float4 d = ok2 ? *(const float4*)(p2 + kc + lk + 4) : z4;
            cvt8(a, b, ah1, al1);
            cvt8(c, d, ah2, al2);
        } else {
            const f16x8 zf = {};
            ah1 = ok1 ? *(const f16x8*)(Ahi + (size_t)r1 * 128 + kc + lk) : zf;
            al1 = ok1 ? *(const f16x8*)(Alo + (size_t)r1 * 128 + kc + lk) : zf;
            ah2 = ok2 ? *(const f16x8*)(Ahi + (size_t)r2 * 128 + kc + lk) : zf;
            al2 = ok2 ? *(const f16x8*)(Alo + (size_t)r2 * 128 + kc + lk) : zf;
        }
        f16x8 bh1 = *(const f16x8*)(Bhi + (size_t)lr * 128 + kc + lk);
        f16x8 bl1 = *(const f16x8*)(Blo + (size_t)lr * 128 + kc + lk);
        f16x8 bh2 = *(const f16x8*)(Bhi + (size_t)(lr + 64) * 128 + kc + lk);
        f16x8 bl2 = *(const f16x8*)(Blo + (size_t)(lr + 64) * 128 + kc + lk);
        __syncthreads();
        *(f16x8*)&sA[0][lr][lk]      = ah1;
        *(f16x8*)&sA[1][lr][lk]      = al1;
        *(f16x8*)&sA[0][lr + 64][lk] = ah2;
        *(f16x8*)&sA[1][lr + 64][lk] = al2;
        *(f16x8*)&sB[0][lr][lk]      = bh1;
        *(f16x8*)&sB[1][lr][lk]      = bl1;
        *(f16x8*)&sB[0][lr + 64][lk] = bh2;
        *(f16x8*)&sB[1][lr + 64][lk] = bl2;
        __syncthreads();

        f16x8 afh[4], afl[4], bfh[4], bfl[4];
#pragma unroll
        for (int mi = 0; mi < 4; mi++) {
            afh[mi] = *(const f16x8*)&sA[0][wm + mi * 16 + fm][quad * 8];
            afl[mi] = *(const f16x8*)&sA[1][wm + mi * 16 + fm][quad * 8];
        }
#pragma unroll
        for (int ni = 0; ni < 4; ni++) {
            bfh[ni] = *(const f16x8*)&sB[0][wn + ni * 16 + fm][quad * 8];
            bfl[ni] = *(const f16x8*)&sB[1][wn + ni * 16 + fm][quad * 8];
        }
#pragma unroll
        for (int mi = 0; mi < 4; mi++)
#pragma unroll
            for (int ni = 0; ni < 4; ni++) {
                acc[mi][ni] = __builtin_amdgcn_mfma_f32_16x16x32_f16(afh[mi], bfh[ni], acc[mi][ni], 0, 0, 0);
                acc[mi][ni] = __builtin_amdgcn_mfma_f32_16x16x32_f16(afh[mi], bfl[ni], acc[mi][ni], 0, 0, 0);
                acc[mi][ni] = __builtin_amdgcn_mfma_f32_16x16x32_f16(afl[mi], bfh[ni], acc[mi][ni], 0, 0, 0);
            }
    }

#pragma unroll
    for (int mi = 0; mi < 4; mi++)
#pragma unroll
        for (int reg = 0; reg < 4; reg++) {
            int r = row0 + wm + mi * 16 + quad * 4 + reg;
            if (r >= M) continue;
#pragma unroll
            for (int ni = 0; ni < 4; ni++)
                C[(size_t)r * 128 + wn + ni * 16 + fm] = acc[mi][ni][reg];
        }
}

// ---------------- generic fp32 GEMM (head GEMMs) ---------------------------
__global__ __launch_bounds__(256) void k_gemm(
        const float* __restrict__ A, const float* __restrict__ B,
        const float* __restrict__ bias, float* __restrict__ C,
        int M, int Nn, int K, int ldc, int act) {
    __shared__ float As[16][64];
    __shared__ float Bs[16][68];
    int tid = threadIdx.x;
    int tx = tid & 15, ty = tid >> 4;
    int row0 = blockIdx.x * 64, col0 = blockIdx.y * 64;
    float acc[4][4] = {};
    int arow = tid >> 2;
    int acol = (tid & 3) * 4;
    int brow = tid >> 4;
    int bcol = (tid & 15) * 4;

    for (int k0 = 0; k0 < K; k0 += 16) {
        float4 av = make_float4(0.f, 0.f, 0.f, 0.f);
        int ar = row0 + arow;
        if (ar < M) av = *(const float4*)(A + (size_t)ar * K + k0 + acol);
        As[acol + 0][arow] = av.x;
        As[acol + 1][arow] = av.y;
        As[acol + 2][arow] = av.z;
        As[acol + 3][arow] = av.w;

        float4 bv = make_float4(0.f, 0.f, 0.f, 0.f);
        const float* Brow = B + (size_t)(k0 + brow) * Nn;
        int bc = col0 + bcol;
        if (bc + 3 < Nn) {
            bv = *(const float4*)(Brow + bc);
        } else {
            if (bc     < Nn) bv.x = Brow[bc];
            if (bc + 1 < Nn) bv.y = Brow[bc + 1];
            if (bc + 2 < Nn) bv.z = Brow[bc + 2];
        }
        Bs[brow][bcol + 0] = bv.x;
        Bs[brow][bcol + 1] = bv.y;
        Bs[brow][bcol + 2] = bv.z;
        Bs[brow][bcol + 3] = bv.w;
        __syncthreads();

#pragma unroll
        for (int k = 0; k < 16; k++) {
            float4 a = *(const float4*)&As[k][ty * 4];
            float4 b = *(const float4*)&Bs[k][tx * 4];
            acc[0][0] += a.x * b.x; acc[0][1] += a.x * b.y; acc[0][2] += a.x * b.z; acc[0][3] += a.x * b.w;
            acc[1][0] += a.y * b.x; acc[1][1] += a.y * b.y; acc[1][2] += a.y * b.z; acc[1][3] += a.y * b.w;
            acc[2][0] += a.z * b.x; acc[2][1] += a.z * b.y; acc[2][2] += a.z * b.z; acc[2][3] += a.z * b.w;
            acc[3][0] += a.w * b.x; acc[3][1] += a.w * b.y; acc[3][2] += a.w * b.z; acc[3][3] += a.w * b.w;
        }
        __syncthreads();
    }

#pragma unroll
    for (int i = 0; i < 4; i++) {
        int r = row0 + ty * 4 + i;
        if (r >= M) continue;
#pragma unroll
        for (int j = 0; j < 4; j++) {
            int c = col0 + tx * 4 + j;
            if (c >= Nn) continue;
            float v = acc[i][j];
            if (bias) v += bias[c];
            if (act) v = fmaxf(v, 0.0f);
            C[(size_t)r * ldc + c] = v;
        }
    }
}

// ---------------- pool GEMM: zcat[g, side*128+c] = (pool/cnt) @ W3 + b3 ----
// blockIdx.z = side; fuses the mean-divide into the A staging.
__global__ __launch_bounds__(256) void k_gemm_pool(
        const float* __restrict__ pool, const float* __restrict__ cnt_g,
        const float* __restrict__ W, const float* __restrict__ bias,
        float* __restrict__ zcat) {
    __shared__ float As[16][64];
    __shared__ float Bs[16][68];
    int side = blockIdx.z;
    const float* A = pool + (size_t)side * NGRAPH * HDIM;
    const float* cg = cnt_g + side * NGRAPH;
    int tid = threadIdx.x;
    int tx = tid & 15, ty = tid >> 4;
    int row0 = blockIdx.x * 64, col0 = blockIdx.y * 64;
    float acc[4][4] = {};
    int arow = tid >> 2;
    int acol = (tid & 3) * 4;
    int brow = tid >> 4;
    int bcol = (tid & 15) * 4;

    for (int k0 = 0; k0 < 128; k0 += 16) {
        int ar = row0 + arow;
        float sc = 1.0f / fmaxf(cg[ar], 1.0f);
        float4 av = *(const float4*)(A + (size_t)ar * 128 + k0 + acol);
        As[acol + 0][arow] = av.x * sc;
        As[acol + 1][arow] = av.y * sc;
        As[acol + 2][arow] = av.z * sc;
        As[acol + 3][arow] = av.w * sc;

        float4 bv = *(const float4*)(W + (size_t)(k0 + brow) * 128 + col0 + bcol);
        Bs[brow][bcol + 0] = bv.x;
        Bs[brow][bcol + 1] = bv.y;
        Bs[brow][bcol + 2] = bv.z;
        Bs[brow][bcol + 3] = bv.w;
        __syncthreads();

#pragma unroll
        for (int k = 0; k < 16; k++) {
            float4 a = *(const float4*)&As[k][ty * 4];
            float4 b = *(const float4*)&Bs[k][tx * 4];
            acc[0][0] += a.x * b.x; acc[0][1] += a.x * b.y; acc[0][2] += a.x * b.z; acc[0][3] += a.x * b.w;
            acc[1][0] += a.y * b.x; acc[1][1] += a.y * b.y; acc[1][2] += a.y * b.z; acc[1][3] += a.y * b.w;
            acc[2][0] += a.z * b.x; acc[2][1] += a.z * b.y; acc[2][2] += a.z * b.z; acc[2][3] += a.z * b.w;
            acc[3][0] += a.w * b.x; acc[3][1] += a.w * b.y; acc[3][2] += a.w * b.z; acc[3][3] += a.w * b.w;
        }
        __syncthreads();
    }

#pragma unroll
    for (int i = 0; i < 4; i++) {
        int r = row0 + ty * 4 + i;
#pragma unroll
        for (int j = 0; j < 4; j++) {
            int c = col0 + tx * 4 + j;
            zcat[(size_t)r * 256 + side * 128 + c] = acc[i][j] + bias[c];
        }
    }
}

// ---------------- CSR aggregation: prefetched scalar edge records ----------
// One wave per node. Edge records for block k+1 are s_loaded during block
// k's gathers, so at loop top the 8 gather addresses are already in SGPRs
// and issue with zero wait. Tail slots clamp to the last valid edge
// (duplicate line -> MSHR-merged) with weight 0.
// MODE 0: out = relu(agg+bias), split-f16 (PACK=1) or fp32 (PACK=0).
// MODE 2: pool[gid] += agg (atomic).
template <int MODE, int PACK>
__global__ __launch_bounds__(256) void k_agg(
        const float* __restrict__ H, const float* __restrict__ dinv,
        const int* __restrict__ row_ptr, const int2* __restrict__ edges,
        const float* __restrict__ bias,
        _Float16* __restrict__ outHi, _Float16* __restrict__ outLo,
        float* __restrict__ outF,
        const int* __restrict__ bt0, const int* __restrict__ bt1,
        int goff0, int nnodes, int nside, float* __restrict__ pool) {
    int wave = threadIdx.x >> 6, lane = threadIdx.x & 63;
    int node = blockIdx.x * 4 + wave;
    if (node >= nnodes) return;

    float di = dinv[node];
    float2 hv = ((const float2*)(H + (size_t)node * HDIM))[lane];
    float wself = di * di;
    float ax = hv.x * wself;
    float ay = hv.y * wself;

    int rs = __builtin_amdgcn_readfirstlane(row_ptr[node]);
    int re = __builtin_amdgcn_readfirstlane(row_ptr[node + 1]);

    int2 E0, E1, E2, E3, E4, E5, E6, E7;
    if (rs < re) {
        int nrem = re - rs, m = nrem - 1;
        E0 = edges[rs];
        E1 = edges[rs + (1 < nrem ? 1 : m)];
        E2 = edges[rs + (2 < nrem ? 2 : m)];
        E3 = edges[rs + (3 < nrem ? 3 : m)];
        E4 = edges[rs + (4 < nrem ? 4 : m)];
        E5 = edges[rs + (5 < nrem ? 5 : m)];
        E6 = edges[rs + (6 < nrem ? 6 : m)];
        E7 = edges[rs + (7 < nrem ? 7 : m)];
    }

    for (int base = rs; base < re; base += 8) {
        // prefetch next block's records (uniform branch)
        int nb = base + 8;
        int2 P0 = E0, P1 = E1, P2 = E2, P3 = E3, P4 = E4, P5 = E5, P6 = E6, P7 = E7;
        if (nb < re) {
            int nr2 = re - nb, m2 = nr2 - 1;
            P0 = edges[nb];
            P1 = edges[nb + (1 < nr2 ? 1 : m2)];
            P2 = edges[nb + (2 < nr2 ? 2 : m2)];
            P3 = edges[nb + (3 < nr2 ? 3 : m2)];
            P4 = edges[nb + (4 < nr2 ? 4 : m2)];
            P5 = edges[nb + (5 < nr2 ? 5 : m2)];
            P6 = edges[nb + (6 < nr2 ? 6 : m2)];
            P7 = edges[nb + (7 < nr2 ? 7 : m2)];
        }

        // gathers: addresses already resident from previous iteration
        float2 v0 = ((const float2*)(H + (size_t)E0.x * HDIM))[lane];
        float2 v1 = ((const float2*)(H + (size_t)E1.x * HDIM))[lane];
        float2 v2 = ((const float2*)(H + (size_t)E2.x * HDIM))[lane];
        float2 v3 = ((const float2*)(H + (size_t)E3.x * HDIM))[lane];
        float2 v4 = ((const float2*)(H + (size_t)E4.x * HDIM))[lane];
        float2 v5 = ((const float2*)(H + (size_t)E5.x * HDIM))[lane];
        float2 v6 = ((const float2*)(H + (size_t)E6.x * HDIM))[lane];
        float2 v7 = ((const float2*)(H + (size_t)E7.x * HDIM))[lane];

        int nrem = re - base;
        float w0 = __int_as_float(E0.y);
        float w1 = 1 < nrem ? __int_as_float(E1.y) : 0.f;
        float w2 = 2 < nrem ? __int_as_float(E2.y) : 0.f;
        float w3 = 3 < nrem ? __int_as_float(E3.y) : 0.f;
        float w4 = 4 < nrem ? __int_as_float(E4.y) : 0.f;
        float w5 = 5 < nrem ? __int_as_float(E5.y) : 0.f;
        float w6 = 6 < nrem ? __int_as_float(E6.y) : 0.f;
        float w7 = 7 < nrem ? __int_as_float(E7.y) : 0.f;

        ax = fmaf(v0.x, w0, ax); ay = fmaf(v0.y, w0, ay);
        ax = fmaf(v1.x, w1, ax); ay = fmaf(v1.y, w1, ay);
        ax = fmaf(v2.x, w2, ax); ay = fmaf(v2.y, w2, ay);
        ax = fmaf(v3.x, w3, ax); ay = fmaf(v3.y, w3, ay);
        ax = fmaf(v4.x, w4, ax); ay = fmaf(v4.y, w4, ay);
        ax = fmaf(v5.x, w5, ax); ay = fmaf(v5.y, w5, ay);
        ax = fmaf(v6.x, w6, ax); ay = fmaf(v6.y, w6, ay);
        ax = fmaf(v7.x, w7, ax); ay = fmaf(v7.y, w7, ay);

        E0 = P0; E1 = P1; E2 = P2; E3 = P3;
        E4 = P4; E5 = P5; E6 = P6; E7 = P7;
    }

    if (MODE == 2) {
        int g = (node < nside) ? bt0[node] + goff0 : bt1[node - nside] + NGRAPH;
        float* p = pool + (size_t)g * HDIM + lane * 2;
        atomicAdd(p,     ax);
        atomicAdd(p + 1, ay);
    } else {
        float ox = fmaxf(ax + bias[lane * 2],     0.0f);
        float oy = fmaxf(ay + bias[lane * 2 + 1], 0.0f);
        if (PACK) {
            _Float16 hx = (_Float16)ox, hy = (_Float16)oy;
            _Float16 lx = (_Float16)(ox - (float)hx), ly = (_Float16)(oy - (float)hy);
            union { _Float16 h[2]; unsigned u; } ph, pl;
            ph.h[0] = hx; ph.h[1] = hy;
            pl.h[0] = lx; pl.h[1] = ly;
            ((unsigned*)(outHi + (size_t)node * HDIM))[lane] = ph.u;
            ((unsigned*)(outLo + (size_t)node * HDIM))[lane] = pl.u;
        } else {
            ((float2*)(outF + (size_t)node * HDIM))[lane] = make_float2(ox, oy);
        }
    }
}

extern "C" void kernel_launch(void* const* d_in, const int* in_sizes, int n_in,
                              void* d_out, int out_size, void* d_ws, size_t ws_size,
                              hipStream_t stream) {
    (void)in_sizes; (void)n_in; (void)out_size;

    const float* x[2]  = {(const float*)d_in[0], (const float*)d_in[1]};
    const int*   ei[2] = {(const int*)d_in[2], (const int*)d_in[3]};
    const int*   bt[2] = {(const int*)d_in[4], (const int*)d_in[5]};
    const float* W1  = (const float*)d_in[6];  const float* b1  = (const float*)d_in[7];
    const float* W2  = (const float*)d_in[8];  const float* b2  = (const float*)d_in[9];
    const float* W3  = (const float*)d_in[10]; const float* b3  = (const float*)d_in[11];
    const float* Wc1 = (const float*)d_in[12]; const float* bc1 = (const float*)d_in[13];
    const float* Wc2 = (const float*)d_in[14]; const float* bc2 = (const float*)d_in[15];
    const float* Wc3 = (const float*)d_in[16]; const float* bc3 = (const float*)d_in[17];
    float* out = (float*)d_out;

    const bool batched = ws_size >= 120ull * 1000 * 1000;
    const int NN = batched ? 2 * N_NODES : N_NODES;
    const int NE = batched ? 2 * E_EDGES : E_EDGES;

    char* ws = (char*)d_ws;
    size_t off = 0;
    auto carve = [&](size_t bytes) -> char* {
        char* p = ws + off;
        off += (bytes + 255) & ~(size_t)255;
        return p;
    };

    int*   edge_cnt = (int*)  carve((size_t)NN * 4);
    int*   fill_cnt = (int*)  carve((size_t)NN * 4);
    float* pool_s   = (float*)carve((size_t)2 * NGRAPH * HDIM * 4);
    float* cnt_g    = (float*)carve((size_t)2 * NGRAPH * 4);
    float* dinv     = (float*)carve((size_t)NN * 4);
    int*   row_ptr  = (int*)  carve((size_t)(NN + 1) * 4);
    int2*  edges    = (int2*) carve((size_t)NE * 8);
    int*   blksum   = (int*)  carve(1024 * 4);
    _Float16* wt    = (_Float16*)carve(4 * 128 * 128 * 2);     // W1t hi/lo, W2t hi/lo
    _Float16* hS    = (_Float16*)carve((size_t)NN * HDIM * 4); // split planes OR fp32 alias
    float* hA       = (float*)carve((size_t)NN * HDIM * 4);
    float* zcat     = (float*)carve((size_t)NGRAPH * 2 * HDIM * 4);
    float* z1       = (float*)carve((size_t)NGRAPH * 4 * HDIM * 4);
    float* z2       = (float*)carve((size_t)NGRAPH * 2 * HDIM * 4);

    _Float16* w1hi = wt;
    _Float16* w1lo = wt + 128 * 128;
    _Float16* w2hi = wt + 2 * 128 * 128;
    _Float16* w2lo = wt + 3 * 128 * 128;
    _Float16* hShi = hS;
    _Float16* hSlo = hS + (size_t)NN * HDIM;
    float*    hSf  = (float*)hS;

    int zeroA_words = (int)(((char*)pool_s - (char*)edge_cnt) / 4);
    int zeroB_words = (int)(((char*)dinv   - (char*)pool_s)   / 4);

    const int gblk = (NN + 127) / 128;

    if (batched) {
        const int nscan = (2 * N_NODES + 511) / 512;
        const int ablk  = (2 * N_NODES + 3) / 4;

        k_prep<<<512, 256, 0, stream>>>(edge_cnt, zeroA_words, (int*)pool_s, zeroB_words,
                                        W1, W2, w1hi, w1lo, w2hi, w2lo);
        k_hist<<<1024, 256, 0, stream>>>(ei[0] + E_EDGES, ei[1] + E_EDGES,
                                         2 * E_EDGES, N_NODES, edge_cnt);
        k_scan_a<<<nscan, 512, 0, stream>>>(edge_cnt, row_ptr, blksum, dinv,
                                            bt[0], bt[1], 0, 2 * N_NODES, N_NODES, cnt_g);
        k_scan_b<<<1, 512, 0, stream>>>(blksum, nscan);
        k_scan_c<<<nscan, 512, 0, stream>>>(row_ptr, blksum, 2 * N_NODES, 2 * E_EDGES);
        k_fill<<<1024, 256, 0, stream>>>(ei[0], ei[1], ei[0] + E_EDGES, ei[1] + E_EDGES,
                                         2 * E_EDGES, N_NODES, row_ptr, fill_cnt, dinv, edges);

        k_gemm_split<1><<<gblk, 256, 0, stream>>>(x[0], x[1], N_NODES,
                                                  nullptr, nullptr, w1hi, w1lo, hA, 2 * N_NODES);
        k_agg<0, 1><<<ablk, 256, 0, stream>>>(hA, dinv, row_ptr, edges, b1,
                                              hShi, hSlo, nullptr, bt[0], bt[1], 0,
                                              2 * N_NODES, N_NODES, nullptr);
        k_gemm_split<0><<<gblk, 256, 0, stream>>>(nullptr, nullptr, 0,
                                                  hShi, hSlo, w2hi, w2lo, hA, 2 * N_NODES);
        k_agg<0, 0><<<ablk, 256, 0, stream>>>(hA, dinv, row_ptr, edges, b2,
                                              nullptr, nullptr, hSf, bt[0], bt[1], 0,
                                              2 * N_NODES, N_NODES, nullptr);
        k_agg<2, 0><<<ablk, 256, 0, stream>>>(hSf, dinv, row_ptr, edges, nullptr,
                                              nullptr, nullptr, nullptr, bt[0], bt[1], 0,
                                              2 * N_NODES, N_NODES, pool_s);
    } else {
        const int nscan = (N_NODES + 511) / 512;
        const int ablk  = (N_NODES + 3) / 4;

        k_prep<<<512, 256, 0, stream>>>(edge_cnt, zeroA_words, (int*)pool_s, zeroB_words,
                                        W1, W2, w1hi, w1lo, w2hi, w2lo);
        for (int s = 0; s < 2; ++s) {
            const int* esrc = ei[s];
            const int* edst = ei[s] + E_EDGES;
            int goff = s * NGRAPH;

            if (s == 1)   // re-zero edge_cnt / fill_cnt for side 2
                k_prep<<<512, 256, 0, stream>>>(edge_cnt, zeroA_words, (int*)pool_s, 0,
                                                W1, W2, w1hi, w1lo, w2hi, w2lo);
            k_hist<<<512, 256, 0, stream>>>(edst, edst, E_EDGES, 0, edge_cnt);
            k_scan_a<<<nscan, 512, 0, stream>>>(edge_cnt, row_ptr, blksum, dinv,
                                                bt[s], bt[s], goff, N_NODES, N_NODES, cnt_g);
            k_scan_b<<<1, 512, 0, stream>>>(blksum, nscan);
            k_scan_c<<<nscan, 512, 0, stream>>>(row_ptr, blksum, N_NODES, E_EDGES);
            k_fill<<<512, 256, 0, stream>>>(esrc, esrc, edst, edst, E_EDGES, 0,
                                            row_ptr, fill_cnt, dinv, edges);

            k_gemm_split<1><<<gblk, 256, 0, stream>>>(x[s], x[s], N_NODES,
                                                      nullptr, nullptr, w1hi, w1lo, hA, N_NODES);
            k_agg<0, 1><<<ablk, 256, 0, stream>>>(hA, dinv, row_ptr, edges, b1,
                                                  hShi, hSlo, nullptr, bt[s], bt[s], goff,
                                                  N_NODES, N_NODES, nullptr);
            k_gemm_split<0><<<gblk, 256, 0, stream>>>(nullptr, nullptr, 0,
                                                      hShi, hSlo, w2hi, w2lo, hA, N_NODES);
            k_agg<0, 0><<<ablk, 256, 0, stream>>>(hA, dinv, row_ptr, edges, b2,
                                                  nullptr, nullptr, hSf, bt[s], bt[s], goff,
                                                  N_NODES, N_NODES, nullptr);
            k_agg<2, 0><<<ablk, 256, 0, stream>>>(hSf, dinv, row_ptr, edges, nullptr,
                                                  nullptr, nullptr, nullptr, bt[s], bt[s], goff,
                                                  N_NODES, N_NODES, pool_s);
        }
    }

    // pooled mean -> @W3 + b3 -> zcat (both sides in one launch)
    k_gemm_pool<<<dim3(NGRAPH / 64, 2, 2), 256, 0, stream>>>(pool_s, cnt_g, W3, b3, zcat);

    // MLP head
    k_gemm<<<dim3(NGRAPH / 64, (4 * HDIM) / 64), 256, 0, stream>>>(zcat, Wc1, bc1, z1, NGRAPH, 4 * HDIM, 2 * HDIM, 4 * HDIM, 1);
    k_gemm<<<dim3(NGRAPH / 64, (2 * HDIM) / 64), 256, 0, stream>>>(z1, Wc2, bc2, z2, NGRAPH, 2 * HDIM, 4 * HDIM, 2 * HDIM, 1);
    k_gemm<<<dim3(NGRAPH / 64, 1), 256, 0, stream>>>(z2, Wc3, bc3, out, NGRAPH, OUTC, 2 * HDIM, OUTC, 0);
}